// Round 12
// baseline (2567.734 us; speedup 1.0000x reference)
//
#include <hip/hip_runtime.h>
#include <hip/hip_bf16.h>
#include <cmath>

#define LATENT 6368
#define TSTEPS 64
#define NDATA 16
#define NPANEL 398   /* LATENT/16 */
#define KSPLIT 8
#define NCHUNK 199   /* LATENT/32 */
#define CPS 25       /* ceil(199/8) (fallback) */
#define NTILE (NPANEL*KSPLIT)
#define KBLK 796     /* LATENT/8 */
#define AGENT __HIP_MEMORY_SCOPE_AGENT

typedef __attribute__((ext_vector_type(8))) short short8v;
typedef __attribute__((ext_vector_type(4))) float floatx4;

__device__ __forceinline__ unsigned short f2bf(float x) {
    union { float f; unsigned u; } c; c.f = x;
    unsigned r = (c.u + 0x7FFFu + ((c.u >> 16) & 1u)) >> 16;
    return (unsigned short)r;
}
__device__ __forceinline__ float bf2f(unsigned short h) {
    union { unsigned u; float f; } c; c.u = ((unsigned)h) << 16; return c.f;
}

// ---- agent-coherent (sc1, L2-bypass) accessors for cross-block mutable data ----
__device__ __forceinline__ float ldfc(const float* p) {
    return __hip_atomic_load(p, __ATOMIC_RELAXED, AGENT);
}
__device__ __forceinline__ void stfc(float* p, float v) {
    __hip_atomic_store(p, v, __ATOMIC_RELAXED, AGENT);
}
__device__ __forceinline__ void stu16c(unsigned short* p, unsigned short v) {
    __hip_atomic_store(p, v, __ATOMIC_RELAXED, AGENT);
}

// ---------- pass 1: per-row scale S[r] = max|E_row|/32767 ----------
__global__ __launch_bounds__(64) void row_scale(const float* __restrict__ A,
                                                float* __restrict__ S) {
    int row = blockIdx.x;
    int lane = threadIdx.x;
    const float* Ar = A + (size_t)row * LATENT;
    float m = 0.f;
    for (int i = 0; i < 25; ++i) {
        int idx = i * 256 + lane * 4;
        if (idx + 4 <= LATENT) {
            float4 v = *reinterpret_cast<const float4*>(Ar + idx);
            float a0 = v.x - (idx + 0 == row ? 1.f : 0.f);
            float a1 = v.y - (idx + 1 == row ? 1.f : 0.f);
            float a2 = v.z - (idx + 2 == row ? 1.f : 0.f);
            float a3 = v.w - (idx + 3 == row ? 1.f : 0.f);
            m = fmaxf(m, fmaxf(fmaxf(fabsf(a0), fabsf(a1)), fmaxf(fabsf(a2), fabsf(a3))));
        }
    }
#pragma unroll
    for (int o = 32; o; o >>= 1) m = fmaxf(m, __shfl_xor(m, o, 64));
    if (lane == 0) S[row] = fmaxf(m, 1e-30f) * (1.0f / 32767.0f);
}

// ---------- pass 2: quantize E to int16, fragment-linear ----------
__global__ __launch_bounds__(256) void convert_Eq(const float* __restrict__ A,
                                                  const float* __restrict__ S,
                                                  short* __restrict__ Eq,
                                                  int total) {
    int t = blockIdx.x * 256 + threadIdx.x;
    if (t >= total) return;                    // LATENT*KBLK % 256 != 0 (R7 lesson)
    int row = t / KBLK;
    int kb  = t - row * KBLK;
    const float4* src = reinterpret_cast<const float4*>(A + (size_t)row * LATENT + kb * 8);
    float4 v0 = src[0];
    float4 v1 = src[1];
    float v[8] = {v0.x, v0.y, v0.z, v0.w, v1.x, v1.y, v1.z, v1.w};
    int jd = row - kb * 8;
    if (jd >= 0 && jd < 8) v[jd] -= 1.0f;
    float inv = 1.0f / S[row];
    union { short8v s; short q[8]; } o;
#pragma unroll
    for (int j = 0; j < 8; ++j) {
        float qf = rintf(v[j] * inv);
        qf = fminf(fmaxf(qf, -32767.f), 32767.f);
        o.q[j] = (short)qf;
    }
    int p = row >> 4, rowl = row & 15, c = kb >> 2, kgrp = kb & 3;
    int lane = kgrp * 16 + rowl;
    *reinterpret_cast<short8v*>(Eq + ((size_t)(p * NCHUNK + c)) * 512 + lane * 8) = o.s;
}

// Packed theta^T (hi rows 0..7, lo rows 8..15). TT writes MUST be sc1 (no-allocate):
// the persistent kernel reads theta with nt loads, which are only coherent if theta
// lines are never allocated in any L2.
__global__ __launch_bounds__(256) void init_theta(const float* __restrict__ th0,
                                                  float* __restrict__ T0,
                                                  unsigned short* __restrict__ TTA) {
    int r = blockIdx.x * blockDim.x + threadIdx.x;
    if (r >= LATENT) return;
    float v = th0[r];
#pragma unroll
    for (int b = 0; b < 8; ++b) T0[r * 8 + b] = v;
    unsigned short hb = f2bf(v);
    unsigned short lb = f2bf(v - bf2f(hb));
#pragma unroll
    for (int n = 0; n < 8; ++n) {
        stu16c(&TTA[n * LATENT + r], hb);
        stu16c(&TTA[(n + 8) * LATENT + r], lb);
    }
}

// ---------- wave-local MLP (plain loads; fallback path only) ----------
__device__ void mlp_batch(const float* __restrict__ Tcur, const float* __restrict__ ts,
                          float* __restrict__ mwrite, float* __restrict__ ys,
                          int i, int b, int lane) {
    float tc = ts[b * TSTEPS + i];
    float tp = (i == 0) ? -ts[b * TSTEPS + 1] : ts[b * TSTEPS + i - 1];
    float rin = 2.f * tc - tp;
    float h0 = fmaxf(Tcur[(size_t)lane * 8 + b] * rin + Tcur[(size_t)(64 + lane) * 8 + b], 0.f);
    float h1 = Tcur[(size_t)(4224 + lane) * 8 + b];
#pragma unroll 8
    for (int k = 0; k < 64; ++k)
        h1 += Tcur[(size_t)(128 + lane * 64 + k) * 8 + b] * __shfl(h0, k, 64);
    h1 = fmaxf(h1, 0.f);
    float o = 0.f;
    if (lane < 32) o = Tcur[(size_t)(6336 + lane) * 8 + b];
#pragma unroll 8
    for (int k = 0; k < 64; ++k) {
        float hk = __shfl(h1, k, 64);
        if (lane < 32) o += Tcur[(size_t)(4288 + lane * 64 + k) * 8 + b] * hk;
    }
    if (lane < 32) {
        float z = tanhf(o);
        float res;
        if (lane < 16) { res = z; mwrite[b * NDATA + lane] = z; }
        else           { res = log1pf(expf(z)); }
        ys[(size_t)b * (TSTEPS * 32) + (size_t)i * 32 + lane] = res;
    }
}

// ---------- wave-local MLP, coherent loads (persistent path) ----------
__device__ void mlp_batch_coh(const float* __restrict__ Tcur, const float* __restrict__ ts,
                              float* __restrict__ mwrite, float* __restrict__ ys,
                              int i, int b, int lane) {
    float tc = ts[b * TSTEPS + i];
    float tp = (i == 0) ? -ts[b * TSTEPS + 1] : ts[b * TSTEPS + i - 1];
    float rin = 2.f * tc - tp;
    float h0 = fmaxf(ldfc(&Tcur[(size_t)lane * 8 + b]) * rin
                     + ldfc(&Tcur[(size_t)(64 + lane) * 8 + b]), 0.f);
    float h1 = ldfc(&Tcur[(size_t)(4224 + lane) * 8 + b]);
#pragma unroll 8
    for (int k = 0; k < 64; ++k)
        h1 += ldfc(&Tcur[(size_t)(128 + lane * 64 + k) * 8 + b]) * __shfl(h0, k, 64);
    h1 = fmaxf(h1, 0.f);
    float o = 0.f;
    if (lane < 32) o = ldfc(&Tcur[(size_t)(6336 + lane) * 8 + b]);
#pragma unroll 8
    for (int k = 0; k < 64; ++k) {
        float hk = __shfl(h1, k, 64);
        if (lane < 32) o += ldfc(&Tcur[(size_t)(4288 + lane * 64 + k) * 8 + b]) * hk;
    }
    if (lane < 32) {
        float z = tanhf(o);
        float res;
        if (lane < 16) { res = z; stfc(&mwrite[b * NDATA + lane], z); }
        else           { res = log1pf(expf(z)); }
        ys[(size_t)b * (TSTEPS * 32) + (size_t)i * 32 + lane] = res;
    }
}

// ---------- grid barrier: fence-free (vmcnt drain + relaxed counters) ----------
__device__ __forceinline__ void gsync2(unsigned* grpCnt, unsigned* superCnt,
                                       unsigned* gEpoch, unsigned iter) {
    asm volatile("s_waitcnt vmcnt(0)" ::: "memory");
    __syncthreads();
    if (threadIdx.x == 0) {
        unsigned g = blockIdx.x & 15u;
        unsigned gsz = (g < 8u) ? 13u : 12u;
        unsigned v = __hip_atomic_fetch_add(&grpCnt[g * 32], 1u, __ATOMIC_RELAXED, AGENT);
        if (v == iter * gsz - 1u) {
            unsigned w = __hip_atomic_fetch_add(superCnt, 1u, __ATOMIC_RELAXED, AGENT);
            if (w == iter * 16u - 1u) {
#pragma unroll
                for (int i2 = 0; i2 < 16; ++i2)
                    __hip_atomic_store(&gEpoch[i2 * 32], iter, __ATOMIC_RELAXED, AGENT);
            }
        }
        while (__hip_atomic_load(&gEpoch[g * 32], __ATOMIC_RELAXED, AGENT) < iter)
            __builtin_amdgcn_s_sleep(4);
    }
    __syncthreads();
}

// exact int16 -> bf16(hi8)*256 + bf16(lo8); 2 panels share one theta fragment
#define COMP2(EA, EB, TP) do {                                                    \
    union { short8v sv; unsigned short us[8]; } HA, LA, HB, LB;                   \
    _Pragma("unroll")                                                             \
    for (int j = 0; j < 8; ++j) {                                                 \
        int qa = (EA)[j], qb = (EB)[j];                                           \
        union { float f; unsigned u; } x0, x1, x2, x3;                            \
        x0.f = (float)(qa >> 8);  HA.us[j] = (unsigned short)(x0.u >> 16);        \
        x1.f = (float)(qa & 255); LA.us[j] = (unsigned short)(x1.u >> 16);        \
        x2.f = (float)(qb >> 8);  HB.us[j] = (unsigned short)(x2.u >> 16);        \
        x3.f = (float)(qb & 255); LB.us[j] = (unsigned short)(x3.u >> 16);        \
    }                                                                             \
    acc1A = __builtin_amdgcn_mfma_f32_16x16x32_bf16(HA.sv, (TP), acc1A, 0, 0, 0); \
    acc2A = __builtin_amdgcn_mfma_f32_16x16x32_bf16(LA.sv, (TP), acc2A, 0, 0, 0); \
    acc1B = __builtin_amdgcn_mfma_f32_16x16x32_bf16(HB.sv, (TP), acc1B, 0, 0, 0); \
    acc2B = __builtin_amdgcn_mfma_f32_16x16x32_bf16(LB.sv, (TP), acc2B, 0, 0, 0); \
} while (0)

#define LDE(P)  (*reinterpret_cast<const short8v*>(P))
#define LDNT(P) (__builtin_nontemporal_load(reinterpret_cast<const short8v*>(P)))

// ---------- persistent v6: 199 blocks x 2 panels (theta shared in-register),
// ---------- nt 16B theta loads, fence-free barrier, Eq L2-resident ----------
__global__ __launch_bounds__(1024, 4) void persistent6(
    const short* __restrict__ Eq, const float* __restrict__ S,
    float* __restrict__ T0buf, float* __restrict__ T1buf,
    unsigned short* __restrict__ TTA, unsigned short* __restrict__ TTB,
    float* __restrict__ mb,
    const float* __restrict__ Bmat, const float* __restrict__ xs,
    const float* __restrict__ ts, float* __restrict__ ys,
    unsigned* grpCnt, unsigned* superCnt, unsigned* gEpoch)
{
    __shared__ float red[16][2][16][16];
    __shared__ float ush[17][8];
    int tid = threadIdx.x, blk = blockIdx.x;
    int wave = tid >> 6, lane = tid & 63;
    int rowl = lane & 15, kgrp = lane >> 4;
    // 199 chunks over 16 waves: waves 0..6 get 13, waves 7..15 get 12
    int cs = (wave < 7) ? wave * 13 : 91 + (wave - 7) * 12;
    int nch = (wave < 7) ? 13 : 12;
    int panelA = blk * 2;
    unsigned iter = 0;
    for (int s = 0; s < TSTEPS; ++s) {
        const float* Tc = (s & 1) ? T1buf : T0buf;
        float* Tn       = (s & 1) ? T0buf : T1buf;
        const unsigned short* TTc = (s & 1) ? TTB : TTA;
        unsigned short* TTn       = (s & 1) ? TTA : TTB;
        float* mwrite = mb + (s & 1) * 128;
        const float* mread = mb + ((s & 1) ^ 1) * 128;
        if (blk < 199) {
            if (tid < 136) {
                int b = tid & 7, j = tid >> 3;
                float tc = ts[b * TSTEPS + s];
                float tp = (s == 0) ? -ts[b * TSTEPS + 1] : ts[b * TSTEPS + s - 1];
                float val;
                if (j == 0) val = tc - tp;
                else {
                    int d = j - 1;
                    float xp = (s < 2) ? xs[(b * TSTEPS) * NDATA + d]
                                       : ldfc(&mread[b * NDATA + d]);
                    val = xs[(b * TSTEPS + s) * NDATA + d] - xp;
                }
                ush[j][b] = val;
            }
            floatx4 acc1A = {0.f,0.f,0.f,0.f}, acc2A = {0.f,0.f,0.f,0.f};
            floatx4 acc1B = {0.f,0.f,0.f,0.f}, acc2B = {0.f,0.f,0.f,0.f};
            const short* epA = Eq + ((size_t)(panelA * NCHUNK + cs)) * 512 + lane * 8;
            const short* epB = epA + (size_t)NCHUNK * 512;
            const unsigned short* tq = TTc + (size_t)rowl * LATENT + kgrp * 8 + (size_t)cs * 32;
            short8v a0 = LDE(epA),        a1 = LDE(epA + 512),
                    a2 = LDE(epA + 1024), a3 = LDE(epA + 1536);
            short8v b0 = LDE(epB),        b1 = LDE(epB + 512),
                    b2 = LDE(epB + 1024), b3 = LDE(epB + 1536);
            short8v t0 = LDNT(tq),        t1 = LDNT(tq + 32),
                    t2 = LDNT(tq + 64),   t3 = LDNT(tq + 96);
            int c = 0;
            for (; c + 8 <= nch; c += 4) {
                COMP2(a0, b0, t0); a0 = LDE(epA + 2048); b0 = LDE(epB + 2048); t0 = LDNT(tq + 128);
                COMP2(a1, b1, t1); a1 = LDE(epA + 2560); b1 = LDE(epB + 2560); t1 = LDNT(tq + 160);
                COMP2(a2, b2, t2); a2 = LDE(epA + 3072); b2 = LDE(epB + 3072); t2 = LDNT(tq + 192);
                COMP2(a3, b3, t3); a3 = LDE(epA + 3584); b3 = LDE(epB + 3584); t3 = LDNT(tq + 224);
                epA += 2048; epB += 2048; tq += 128;
            }
            COMP2(a0, b0, t0); COMP2(a1, b1, t1); COMP2(a2, b2, t2); COMP2(a3, b3, t3);
            for (int k2 = 4; c + k2 < nch; ++k2) {
                a0 = LDE(epA + k2 * 512); b0 = LDE(epB + k2 * 512); t0 = LDNT(tq + k2 * 32);
                COMP2(a0, b0, t0);
            }
            // C/D: col(lane&15)=batch-slot, row(kgrp*4+r)=output row
#pragma unroll
            for (int r = 0; r < 4; ++r) {
                red[wave][0][kgrp * 4 + r][rowl] = 256.f * acc1A[r] + acc2A[r];
                red[wave][1][kgrp * 4 + r][rowl] = 256.f * acc1B[r] + acc2B[r];
            }
            __syncthreads();
            if (tid < 256) {
                int m32 = tid >> 3, n = tid & 7;
                int ph = m32 >> 4, m = m32 & 15;
                float sum = 0.f;
#pragma unroll
                for (int w = 0; w < 16; ++w)
                    sum += red[w][ph][m][n] + red[w][ph][m][n + 8];
                int r = blk * 32 + m32;
                float val = ldfc(&Tc[r * 8 + n]) + S[r] * sum;
                const float* Brow = Bmat + r * 17;
#pragma unroll
                for (int j = 0; j < 17; ++j) val += Brow[j] * ush[j][n];
                stfc(&Tn[r * 8 + n], val);
                unsigned short hb = f2bf(val);
                stu16c(&TTn[n * LATENT + r], hb);
                stu16c(&TTn[(n + 8) * LATENT + r], f2bf(val - bf2f(hb)));
            }
        } else {
            if (s >= 1 && wave < 8)
                mlp_batch_coh(Tc, ts, mwrite, ys, s - 1, wave, lane);
        }
        ++iter; gsync2(grpCnt, superCnt, gEpoch, iter);
    }
    if (blk == 199 && wave < 8)
        mlp_batch_coh(T0buf, ts, mb, ys, TSTEPS - 1, wave, lane);
}

// ---------- fallback path (multi-launch, int16 E) ----------
template<bool USE_E>
__global__ __launch_bounds__(128) void partial_kernel(
    const short* __restrict__ Eq, const float* __restrict__ S,
    const float* __restrict__ Af,
    const unsigned short* __restrict__ TTc,
    float* __restrict__ P)
{
    int blk = blockIdx.x;
    int p  = blk >> 3;
    int si = blk & 7;
    int tid = threadIdx.x;
    int wave = tid >> 6;
    int lane = tid & 63;
    int rowl = lane & 15;
    int kgrp = lane >> 4;
    int row = p * 16 + rowl;
    int c0 = si * CPS;
    int c1 = c0 + CPS; if (c1 > NCHUNK) c1 = NCHUNK;
    int nch = c1 - c0;
    int half = (nch + 1) >> 1;
    int csw = c0 + wave * half;
    int cew = csw + half; if (cew > c1) cew = c1;
    floatx4 acc1 = {0.f, 0.f, 0.f, 0.f};
    floatx4 acc2 = {0.f, 0.f, 0.f, 0.f};
    for (int c = csw; c < cew; ++c) {
        int k = c * 32 + kgrp * 8;
        short8v ehf, elf;
        if (USE_E) {
            short8v ev = *reinterpret_cast<const short8v*>(
                Eq + ((size_t)(p * NCHUNK + c)) * 512 + lane * 8);
            union { short8v sv; unsigned short us[8]; } EH, EL;
#pragma unroll
            for (int j = 0; j < 8; ++j) {
                int q = ev[j];
                union { float f; unsigned u; } ch2, cl2;
                ch2.f = (float)(q >> 8);
                cl2.f = (float)(q & 255);
                EH.us[j] = (unsigned short)(ch2.u >> 16);
                EL.us[j] = (unsigned short)(cl2.u >> 16);
            }
            ehf = EH.sv; elf = EL.sv;
        } else {
            const float* ap = Af + (size_t)row * LATENT + k;
            float v[8];
#pragma unroll
            for (int j = 0; j < 8; ++j) v[j] = ap[j];
            int jd = row - k;
            if (jd >= 0 && jd < 8) v[jd] -= 1.0f;
            union { short8v sv; unsigned short us[8]; } ch, cl;
#pragma unroll
            for (int j = 0; j < 8; ++j) {
                unsigned short hb = f2bf(v[j]);
                ch.us[j] = hb;
                cl.us[j] = f2bf(v[j] - bf2f(hb));
            }
            ehf = ch.sv; elf = cl.sv;
        }
        short8v tpf = *reinterpret_cast<const short8v*>(TTc + (size_t)rowl * LATENT + k);
        acc1 = __builtin_amdgcn_mfma_f32_16x16x32_bf16(ehf, tpf, acc1, 0, 0, 0);
        acc2 = __builtin_amdgcn_mfma_f32_16x16x32_bf16(elf, tpf, acc2, 0, 0, 0);
    }
    __shared__ float red[2][16][16];
#pragma unroll
    for (int r = 0; r < 4; ++r)
        red[wave][kgrp * 4 + r][rowl] = USE_E ? (256.f * acc1[r] + acc2[r])
                                              : (acc1[r] + acc2[r]);
    __syncthreads();
    int nn = tid & 15;
    if (nn < 8) {
        for (int mm = tid >> 4; mm < 16; mm += 8) {
            float s2 = red[0][mm][nn] + red[0][mm][nn + 8]
                     + red[1][mm][nn] + red[1][mm][nn + 8];
            if (USE_E) s2 *= S[p * 16 + mm];
            P[((size_t)(p * 8 + si) * 16 + mm) * 8 + nn] = s2;
        }
    }
}

__global__ __launch_bounds__(256) void combine_kernel(
    const float* __restrict__ P,
    const float* __restrict__ Tcur,
    float* __restrict__ Tnxt,
    unsigned short* __restrict__ TTn,
    const float* __restrict__ Bmat,
    const float* __restrict__ xs,
    const float* __restrict__ ts,
    const float* __restrict__ mread,
    float* __restrict__ mwrite,
    float* __restrict__ ys,
    int s, int do_matvec, int do_mlp)
{
    int tid = threadIdx.x;
    if ((int)blockIdx.x < 199) {
        if (!do_matvec) return;
        __shared__ float u[17][8];
        if (tid < 136) {
            int b = tid & 7;
            int j = tid >> 3;
            float tc = ts[b * TSTEPS + s];
            float tp = (s == 0) ? -ts[b * TSTEPS + 1] : ts[b * TSTEPS + s - 1];
            float val;
            if (j == 0) val = tc - tp;
            else {
                int d = j - 1;
                float xp = (s < 2) ? xs[(b * TSTEPS) * NDATA + d] : mread[b * NDATA + d];
                val = xs[(b * TSTEPS + s) * NDATA + d] - xp;
            }
            u[j][b] = val;
        }
        __syncthreads();
        int idx = blockIdx.x * 256 + tid;
        int r = idx >> 3;
        int n = idx & 7;
        int pp = r >> 4, mm = r & 15;
        const float* Pb = P + ((size_t)pp * 8) * 128 + mm * 8 + n;
        float sum = 0.f;
#pragma unroll
        for (int si = 0; si < KSPLIT; ++si) sum += Pb[si * 128];
        float val = Tcur[r * 8 + n] + sum;
        const float* Brow = Bmat + r * 17;
#pragma unroll
        for (int j = 0; j < 17; ++j) val += Brow[j] * u[j][n];
        Tnxt[r * 8 + n] = val;
        unsigned short hb = f2bf(val);
        TTn[n * LATENT + r] = hb;
        TTn[(n + 8) * LATENT + r] = f2bf(val - bf2f(hb));
    } else {
        if (!do_mlp) return;
        int w = tid >> 6, lane = tid & 63;
        for (int it = 0; it < 2; ++it)
            mlp_batch(Tcur, ts, mwrite, ys, s - 1, w * 2 + it, lane);
    }
}

extern "C" void kernel_launch(void* const* d_in, const int* in_sizes, int n_in,
                              void* d_out, int out_size, void* d_ws, size_t ws_size,
                              hipStream_t stream) {
    const float* xs  = (const float*)d_in[0];
    const float* ts  = (const float*)d_in[1];
    const float* A   = (const float*)d_in[2];
    const float* Bm  = (const float*)d_in[3];
    const float* th0 = (const float*)d_in[4];
    float* ys = (float*)d_out;

    char* ws = (char*)d_ws;
    size_t off = 0;
    auto alloc = [&](size_t bytes) {
        void* p = ws + off;
        off += (bytes + 255) & ~(size_t)255;
        return p;
    };
    float* T0 = (float*)alloc((size_t)LATENT * 8 * sizeof(float));
    float* T1 = (float*)alloc((size_t)LATENT * 8 * sizeof(float));
    unsigned short* TTA = (unsigned short*)alloc((size_t)16 * LATENT * 2);
    unsigned short* TTB = (unsigned short*)alloc((size_t)16 * LATENT * 2);
    float* mb = (float*)alloc(2 * 8 * 16 * sizeof(float));
    float* P  = (float*)alloc((size_t)NTILE * 128 * sizeof(float));
    float* S  = (float*)alloc((size_t)LATENT * sizeof(float));
    unsigned* bar = (unsigned*)alloc(8192);
    unsigned* grpCnt   = bar;             // 16 lines x 128B
    unsigned* superCnt = bar + 512;       // own line
    unsigned* gEpoch   = bar + 544;       // 16 lines x 128B
    size_t Ebytes = (size_t)NPANEL * NCHUNK * 512 * 2;   // int16 fragment-linear: 81 MB
    bool useE = (off + Ebytes + 512) <= ws_size;
    short* Eq = nullptr;
    if (useE) {
        Eq = (short*)alloc(Ebytes);
        row_scale<<<dim3(LATENT), dim3(64), 0, stream>>>(A, S);
        int nthr = LATENT * KBLK;         // NOT divisible by 256: ceil + guard
        convert_Eq<<<dim3((nthr + 255) / 256), dim3(256), 0, stream>>>(A, S, Eq, nthr);
    }
    init_theta<<<dim3((LATENT + 255) / 256), dim3(256), 0, stream>>>(th0, T0, TTA);

    hipError_t coop = hipErrorUnknown;
    if (useE) {
        hipMemsetAsync(bar, 0, 8192, stream);
        void* kargs[] = {
            (void*)&Eq, (void*)&S, (void*)&T0, (void*)&T1,
            (void*)&TTA, (void*)&TTB, (void*)&mb, (void*)&Bm, (void*)&xs,
            (void*)&ts, (void*)&ys, (void*)&grpCnt, (void*)&superCnt, (void*)&gEpoch };
        coop = hipLaunchCooperativeKernel((void*)persistent6,
                                          dim3(200), dim3(1024), kargs, 0, stream);
    }
    if (coop != hipSuccess) {
        // fallback: multi-launch path
        float* T[2] = {T0, T1};
        unsigned short* TT[2] = {TTA, TTB};
        for (int s = 0; s <= TSTEPS; ++s) {
            int cur = s & 1, nxt = cur ^ 1;
            float* mwrite = mb + (s & 1) * 128;
            float* mread  = mb + ((s & 1) ^ 1) * 128;
            int dmv = (s < TSTEPS) ? 1 : 0;
            int dml = (s >= 1) ? 1 : 0;
            if (dmv) {
                if (useE)
                    partial_kernel<true><<<dim3(NTILE), dim3(128), 0, stream>>>(
                        Eq, S, A, TT[cur], P);
                else
                    partial_kernel<false><<<dim3(NTILE), dim3(128), 0, stream>>>(
                        Eq, S, A, TT[cur], P);
            }
            combine_kernel<<<dim3(200), dim3(256), 0, stream>>>(
                P, T[cur], T[nxt], TT[nxt],
                Bm, xs, ts, mread, mwrite, ys, s, dmv, dml);
        }
    }
    (void)in_sizes; (void)n_in; (void)out_size;
}

// Round 13
// 2527.658 us; speedup vs baseline: 1.0159x; 1.0159x over previous
//
#include <hip/hip_runtime.h>
#include <hip/hip_bf16.h>
#include <cmath>

#define LATENT 6368
#define TSTEPS 64
#define NDATA 16
#define NPANEL 398   /* LATENT/16 */
#define KSPLIT 8
#define NCHUNK 199   /* LATENT/32 */
#define CPS 25       /* ceil(199/8) (fallback) */
#define NTILE (NPANEL*KSPLIT)
#define KBLK 796     /* LATENT/8 */
#define AGENT __HIP_MEMORY_SCOPE_AGENT

typedef __attribute__((ext_vector_type(8))) short short8v;
typedef __attribute__((ext_vector_type(4))) float floatx4;

__device__ __forceinline__ unsigned short f2bf(float x) {
    union { float f; unsigned u; } c; c.f = x;
    unsigned r = (c.u + 0x7FFFu + ((c.u >> 16) & 1u)) >> 16;
    return (unsigned short)r;
}
__device__ __forceinline__ float bf2f(unsigned short h) {
    union { unsigned u; float f; } c; c.u = ((unsigned)h) << 16; return c.f;
}

// ---- agent-coherent (sc1, LLC-sourced) accessors for cross-block mutable data ----
__device__ __forceinline__ unsigned long long ld64c(const void* p) {
    return __hip_atomic_load((const unsigned long long*)p, __ATOMIC_RELAXED, AGENT);
}
__device__ __forceinline__ short8v ldT16c(const unsigned short* p) {
    union { short8v v; unsigned long long q[2]; } r;
    r.q[0] = ld64c(p);
    r.q[1] = ld64c(p + 4);
    return r.v;
}
__device__ __forceinline__ float ldfc(const float* p) {
    return __hip_atomic_load(p, __ATOMIC_RELAXED, AGENT);
}
__device__ __forceinline__ void stfc(float* p, float v) {
    __hip_atomic_store(p, v, __ATOMIC_RELAXED, AGENT);
}
__device__ __forceinline__ void stu16c(unsigned short* p, unsigned short v) {
    __hip_atomic_store(p, v, __ATOMIC_RELAXED, AGENT);
}

// ---------- pass 1: per-row scale S[r] = max|E_row|/32767 ----------
__global__ __launch_bounds__(64) void row_scale(const float* __restrict__ A,
                                                float* __restrict__ S) {
    int row = blockIdx.x;
    int lane = threadIdx.x;
    const float* Ar = A + (size_t)row * LATENT;
    float m = 0.f;
    for (int i = 0; i < 25; ++i) {
        int idx = i * 256 + lane * 4;
        if (idx + 4 <= LATENT) {
            float4 v = *reinterpret_cast<const float4*>(Ar + idx);
            float a0 = v.x - (idx + 0 == row ? 1.f : 0.f);
            float a1 = v.y - (idx + 1 == row ? 1.f : 0.f);
            float a2 = v.z - (idx + 2 == row ? 1.f : 0.f);
            float a3 = v.w - (idx + 3 == row ? 1.f : 0.f);
            m = fmaxf(m, fmaxf(fmaxf(fabsf(a0), fabsf(a1)), fmaxf(fabsf(a2), fabsf(a3))));
        }
    }
#pragma unroll
    for (int o = 32; o; o >>= 1) m = fmaxf(m, __shfl_xor(m, o, 64));
    if (lane == 0) S[row] = fmaxf(m, 1e-30f) * (1.0f / 32767.0f);
}

// ---------- pass 2: quantize E to int16, fragment-linear ----------
__global__ __launch_bounds__(256) void convert_Eq(const float* __restrict__ A,
                                                  const float* __restrict__ S,
                                                  short* __restrict__ Eq,
                                                  int total) {
    int t = blockIdx.x * 256 + threadIdx.x;
    if (t >= total) return;                    // LATENT*KBLK % 256 != 0 (R7 lesson)
    int row = t / KBLK;
    int kb  = t - row * KBLK;
    const float4* src = reinterpret_cast<const float4*>(A + (size_t)row * LATENT + kb * 8);
    float4 v0 = src[0];
    float4 v1 = src[1];
    float v[8] = {v0.x, v0.y, v0.z, v0.w, v1.x, v1.y, v1.z, v1.w};
    int jd = row - kb * 8;
    if (jd >= 0 && jd < 8) v[jd] -= 1.0f;
    float inv = 1.0f / S[row];
    union { short8v s; short q[8]; } o;
#pragma unroll
    for (int j = 0; j < 8; ++j) {
        float qf = rintf(v[j] * inv);
        qf = fminf(fmaxf(qf, -32767.f), 32767.f);
        o.q[j] = (short)qf;
    }
    int p = row >> 4, rowl = row & 15, c = kb >> 2, kgrp = kb & 3;
    int lane = kgrp * 16 + rowl;
    *reinterpret_cast<short8v*>(Eq + ((size_t)(p * NCHUNK + c)) * 512 + lane * 8) = o.s;
}

// Packed theta^T (hi rows 0..7, lo rows 8..15), written via sc1 (no L2 allocation).
__global__ __launch_bounds__(256) void init_theta(const float* __restrict__ th0,
                                                  float* __restrict__ T0,
                                                  unsigned short* __restrict__ TTA) {
    int r = blockIdx.x * blockDim.x + threadIdx.x;
    if (r >= LATENT) return;
    float v = th0[r];
#pragma unroll
    for (int b = 0; b < 8; ++b) T0[r * 8 + b] = v;
    unsigned short hb = f2bf(v);
    unsigned short lb = f2bf(v - bf2f(hb));
#pragma unroll
    for (int n = 0; n < 8; ++n) {
        stu16c(&TTA[n * LATENT + r], hb);
        stu16c(&TTA[(n + 8) * LATENT + r], lb);
    }
}

// ---------- wave-local MLP (plain loads; fallback path only) ----------
__device__ void mlp_batch(const float* __restrict__ Tcur, const float* __restrict__ ts,
                          float* __restrict__ mwrite, float* __restrict__ ys,
                          int i, int b, int lane) {
    float tc = ts[b * TSTEPS + i];
    float tp = (i == 0) ? -ts[b * TSTEPS + 1] : ts[b * TSTEPS + i - 1];
    float rin = 2.f * tc - tp;
    float h0 = fmaxf(Tcur[(size_t)lane * 8 + b] * rin + Tcur[(size_t)(64 + lane) * 8 + b], 0.f);
    float h1 = Tcur[(size_t)(4224 + lane) * 8 + b];
#pragma unroll 8
    for (int k = 0; k < 64; ++k)
        h1 += Tcur[(size_t)(128 + lane * 64 + k) * 8 + b] * __shfl(h0, k, 64);
    h1 = fmaxf(h1, 0.f);
    float o = 0.f;
    if (lane < 32) o = Tcur[(size_t)(6336 + lane) * 8 + b];
#pragma unroll 8
    for (int k = 0; k < 64; ++k) {
        float hk = __shfl(h1, k, 64);
        if (lane < 32) o += Tcur[(size_t)(4288 + lane * 64 + k) * 8 + b] * hk;
    }
    if (lane < 32) {
        float z = tanhf(o);
        float res;
        if (lane < 16) { res = z; mwrite[b * NDATA + lane] = z; }
        else           { res = log1pf(expf(z)); }
        ys[(size_t)b * (TSTEPS * 32) + (size_t)i * 32 + lane] = res;
    }
}

// ---------- wave-local MLP, coherent loads (persistent path) ----------
__device__ void mlp_batch_coh(const float* __restrict__ Tcur, const float* __restrict__ ts,
                              float* __restrict__ mwrite, float* __restrict__ ys,
                              int i, int b, int lane) {
    float tc = ts[b * TSTEPS + i];
    float tp = (i == 0) ? -ts[b * TSTEPS + 1] : ts[b * TSTEPS + i - 1];
    float rin = 2.f * tc - tp;
    float h0 = fmaxf(ldfc(&Tcur[(size_t)lane * 8 + b]) * rin
                     + ldfc(&Tcur[(size_t)(64 + lane) * 8 + b]), 0.f);
    float h1 = ldfc(&Tcur[(size_t)(4224 + lane) * 8 + b]);
#pragma unroll 8
    for (int k = 0; k < 64; ++k)
        h1 += ldfc(&Tcur[(size_t)(128 + lane * 64 + k) * 8 + b]) * __shfl(h0, k, 64);
    h1 = fmaxf(h1, 0.f);
    float o = 0.f;
    if (lane < 32) o = ldfc(&Tcur[(size_t)(6336 + lane) * 8 + b]);
#pragma unroll 8
    for (int k = 0; k < 64; ++k) {
        float hk = __shfl(h1, k, 64);
        if (lane < 32) o += ldfc(&Tcur[(size_t)(4288 + lane * 64 + k) * 8 + b]) * hk;
    }
    if (lane < 32) {
        float z = tanhf(o);
        float res;
        if (lane < 16) { res = z; stfc(&mwrite[b * NDATA + lane], z); }
        else           { res = log1pf(expf(z)); }
        ys[(size_t)b * (TSTEPS * 32) + (size_t)i * 32 + lane] = res;
    }
}

// ---------- grid barrier: fence-free (vmcnt drain + relaxed counters) ----------
__device__ __forceinline__ void gsync2(unsigned* grpCnt, unsigned* superCnt,
                                       unsigned* gEpoch, unsigned iter) {
    asm volatile("s_waitcnt vmcnt(0)" ::: "memory");
    __syncthreads();
    if (threadIdx.x == 0) {
        unsigned g = blockIdx.x & 15u;
        unsigned gsz = (g < 8u) ? 13u : 12u;
        unsigned v = __hip_atomic_fetch_add(&grpCnt[g * 32], 1u, __ATOMIC_RELAXED, AGENT);
        if (v == iter * gsz - 1u) {
            unsigned w = __hip_atomic_fetch_add(superCnt, 1u, __ATOMIC_RELAXED, AGENT);
            if (w == iter * 16u - 1u) {
#pragma unroll
                for (int i2 = 0; i2 < 16; ++i2)
                    __hip_atomic_store(&gEpoch[i2 * 32], iter, __ATOMIC_RELAXED, AGENT);
            }
        }
        while (__hip_atomic_load(&gEpoch[g * 32], __ATOMIC_RELAXED, AGENT) < iter)
            __builtin_amdgcn_s_sleep(4);
    }
    __syncthreads();
}

// exact int16 -> bf16(hi8)*256 + bf16(lo8); 2 panels share one theta fragment
#define COMP2(EA, EB, TP) do {                                                    \
    union { short8v sv; unsigned short us[8]; } HA, LA, HB, LB;                   \
    _Pragma("unroll")                                                             \
    for (int j = 0; j < 8; ++j) {                                                 \
        int qa = (EA)[j], qb = (EB)[j];                                           \
        union { float f; unsigned u; } x0, x1, x2, x3;                            \
        x0.f = (float)(qa >> 8);  HA.us[j] = (unsigned short)(x0.u >> 16);        \
        x1.f = (float)(qa & 255); LA.us[j] = (unsigned short)(x1.u >> 16);        \
        x2.f = (float)(qb >> 8);  HB.us[j] = (unsigned short)(x2.u >> 16);        \
        x3.f = (float)(qb & 255); LB.us[j] = (unsigned short)(x3.u >> 16);        \
    }                                                                             \
    acc1A = __builtin_amdgcn_mfma_f32_16x16x32_bf16(HA.sv, (TP), acc1A, 0, 0, 0); \
    acc2A = __builtin_amdgcn_mfma_f32_16x16x32_bf16(LA.sv, (TP), acc2A, 0, 0, 0); \
    acc1B = __builtin_amdgcn_mfma_f32_16x16x32_bf16(HB.sv, (TP), acc1B, 0, 0, 0); \
    acc2B = __builtin_amdgcn_mfma_f32_16x16x32_bf16(LB.sv, (TP), acc2B, 0, 0, 0); \
} while (0)

#define LDE(P)  (*reinterpret_cast<const short8v*>(P))

// ---------- persistent v7: 199 blocks x 2 panels (theta shared in-register via
// ---------- sc1 atomic loads — HALF the coherent transactions of R11), fence-free
// ---------- barrier, Eq cached/LLC-resident ----------
__global__ __launch_bounds__(1024, 4) void persistent7(
    const short* __restrict__ Eq, const float* __restrict__ S,
    float* __restrict__ T0buf, float* __restrict__ T1buf,
    unsigned short* __restrict__ TTA, unsigned short* __restrict__ TTB,
    float* __restrict__ mb,
    const float* __restrict__ Bmat, const float* __restrict__ xs,
    const float* __restrict__ ts, float* __restrict__ ys,
    unsigned* grpCnt, unsigned* superCnt, unsigned* gEpoch)
{
    __shared__ float red[16][2][16][16];
    __shared__ float ush[17][8];
    int tid = threadIdx.x, blk = blockIdx.x;
    int wave = tid >> 6, lane = tid & 63;
    int rowl = lane & 15, kgrp = lane >> 4;
    // 199 chunks over 16 waves: waves 0..6 get 13, waves 7..15 get 12
    int cs = (wave < 7) ? wave * 13 : 91 + (wave - 7) * 12;
    int nch = (wave < 7) ? 13 : 12;
    int panelA = blk * 2;
    unsigned iter = 0;
    for (int s = 0; s < TSTEPS; ++s) {
        const float* Tc = (s & 1) ? T1buf : T0buf;
        float* Tn       = (s & 1) ? T0buf : T1buf;
        const unsigned short* TTc = (s & 1) ? TTB : TTA;
        unsigned short* TTn       = (s & 1) ? TTA : TTB;
        float* mwrite = mb + (s & 1) * 128;
        const float* mread = mb + ((s & 1) ^ 1) * 128;
        if (blk < 199) {
            if (tid < 136) {
                int b = tid & 7, j = tid >> 3;
                float tc = ts[b * TSTEPS + s];
                float tp = (s == 0) ? -ts[b * TSTEPS + 1] : ts[b * TSTEPS + s - 1];
                float val;
                if (j == 0) val = tc - tp;
                else {
                    int d = j - 1;
                    float xp = (s < 2) ? xs[(b * TSTEPS) * NDATA + d]
                                       : ldfc(&mread[b * NDATA + d]);
                    val = xs[(b * TSTEPS + s) * NDATA + d] - xp;
                }
                ush[j][b] = val;
            }
            floatx4 acc1A = {0.f,0.f,0.f,0.f}, acc2A = {0.f,0.f,0.f,0.f};
            floatx4 acc1B = {0.f,0.f,0.f,0.f}, acc2B = {0.f,0.f,0.f,0.f};
            const short* epA = Eq + ((size_t)(panelA * NCHUNK + cs)) * 512 + lane * 8;
            const short* epB = epA + (size_t)NCHUNK * 512;
            const unsigned short* tq = TTc + (size_t)rowl * LATENT + kgrp * 8 + (size_t)cs * 32;
            short8v a0 = LDE(epA),        a1 = LDE(epA + 512),
                    a2 = LDE(epA + 1024), a3 = LDE(epA + 1536);
            short8v b0 = LDE(epB),        b1 = LDE(epB + 512),
                    b2 = LDE(epB + 1024), b3 = LDE(epB + 1536);
            short8v t0 = ldT16c(tq),      t1 = ldT16c(tq + 32),
                    t2 = ldT16c(tq + 64), t3 = ldT16c(tq + 96);
            int c = 0;
            for (; c + 8 <= nch; c += 4) {
                COMP2(a0, b0, t0); a0 = LDE(epA + 2048); b0 = LDE(epB + 2048); t0 = ldT16c(tq + 128);
                COMP2(a1, b1, t1); a1 = LDE(epA + 2560); b1 = LDE(epB + 2560); t1 = ldT16c(tq + 160);
                COMP2(a2, b2, t2); a2 = LDE(epA + 3072); b2 = LDE(epB + 3072); t2 = ldT16c(tq + 192);
                COMP2(a3, b3, t3); a3 = LDE(epA + 3584); b3 = LDE(epB + 3584); t3 = ldT16c(tq + 224);
                epA += 2048; epB += 2048; tq += 128;
            }
            COMP2(a0, b0, t0); COMP2(a1, b1, t1); COMP2(a2, b2, t2); COMP2(a3, b3, t3);
            for (int k2 = 4; c + k2 < nch; ++k2) {
                a0 = LDE(epA + k2 * 512); b0 = LDE(epB + k2 * 512); t0 = ldT16c(tq + k2 * 32);
                COMP2(a0, b0, t0);
            }
            // C/D: col(lane&15)=batch-slot, row(kgrp*4+r)=output row
#pragma unroll
            for (int r = 0; r < 4; ++r) {
                red[wave][0][kgrp * 4 + r][rowl] = 256.f * acc1A[r] + acc2A[r];
                red[wave][1][kgrp * 4 + r][rowl] = 256.f * acc1B[r] + acc2B[r];
            }
            __syncthreads();
            if (tid < 256) {
                int m32 = tid >> 3, n = tid & 7;
                int ph = m32 >> 4, m = m32 & 15;
                float sum = 0.f;
#pragma unroll
                for (int w = 0; w < 16; ++w)
                    sum += red[w][ph][m][n] + red[w][ph][m][n + 8];
                int r = blk * 32 + m32;
                float val = ldfc(&Tc[r * 8 + n]) + S[r] * sum;
                const float* Brow = Bmat + r * 17;
#pragma unroll
                for (int j = 0; j < 17; ++j) val += Brow[j] * ush[j][n];
                stfc(&Tn[r * 8 + n], val);
                unsigned short hb = f2bf(val);
                stu16c(&TTn[n * LATENT + r], hb);
                stu16c(&TTn[(n + 8) * LATENT + r], f2bf(val - bf2f(hb)));
            }
        } else {
            if (s >= 1 && wave < 8)
                mlp_batch_coh(Tc, ts, mwrite, ys, s - 1, wave, lane);
        }
        ++iter; gsync2(grpCnt, superCnt, gEpoch, iter);
    }
    if (blk == 199 && wave < 8)
        mlp_batch_coh(T0buf, ts, mb, ys, TSTEPS - 1, wave, lane);
}

// ---------- fallback path (multi-launch, int16 E) ----------
template<bool USE_E>
__global__ __launch_bounds__(128) void partial_kernel(
    const short* __restrict__ Eq, const float* __restrict__ S,
    const float* __restrict__ Af,
    const unsigned short* __restrict__ TTc,
    float* __restrict__ P)
{
    int blk = blockIdx.x;
    int p  = blk >> 3;
    int si = blk & 7;
    int tid = threadIdx.x;
    int wave = tid >> 6;
    int lane = tid & 63;
    int rowl = lane & 15;
    int kgrp = lane >> 4;
    int row = p * 16 + rowl;
    int c0 = si * CPS;
    int c1 = c0 + CPS; if (c1 > NCHUNK) c1 = NCHUNK;
    int nch = c1 - c0;
    int half = (nch + 1) >> 1;
    int csw = c0 + wave * half;
    int cew = csw + half; if (cew > c1) cew = c1;
    floatx4 acc1 = {0.f, 0.f, 0.f, 0.f};
    floatx4 acc2 = {0.f, 0.f, 0.f, 0.f};
    for (int c = csw; c < cew; ++c) {
        int k = c * 32 + kgrp * 8;
        short8v ehf, elf;
        if (USE_E) {
            short8v ev = *reinterpret_cast<const short8v*>(
                Eq + ((size_t)(p * NCHUNK + c)) * 512 + lane * 8);
            union { short8v sv; unsigned short us[8]; } EH, EL;
#pragma unroll
            for (int j = 0; j < 8; ++j) {
                int q = ev[j];
                union { float f; unsigned u; } ch2, cl2;
                ch2.f = (float)(q >> 8);
                cl2.f = (float)(q & 255);
                EH.us[j] = (unsigned short)(ch2.u >> 16);
                EL.us[j] = (unsigned short)(cl2.u >> 16);
            }
            ehf = EH.sv; elf = EL.sv;
        } else {
            const float* ap = Af + (size_t)row * LATENT + k;
            float v[8];
#pragma unroll
            for (int j = 0; j < 8; ++j) v[j] = ap[j];
            int jd = row - k;
            if (jd >= 0 && jd < 8) v[jd] -= 1.0f;
            union { short8v sv; unsigned short us[8]; } ch, cl;
#pragma unroll
            for (int j = 0; j < 8; ++j) {
                unsigned short hb = f2bf(v[j]);
                ch.us[j] = hb;
                cl.us[j] = f2bf(v[j] - bf2f(hb));
            }
            ehf = ch.sv; elf = cl.sv;
        }
        short8v tpf = *reinterpret_cast<const short8v*>(TTc + (size_t)rowl * LATENT + k);
        acc1 = __builtin_amdgcn_mfma_f32_16x16x32_bf16(ehf, tpf, acc1, 0, 0, 0);
        acc2 = __builtin_amdgcn_mfma_f32_16x16x32_bf16(elf, tpf, acc2, 0, 0, 0);
    }
    __shared__ float red[2][16][16];
#pragma unroll
    for (int r = 0; r < 4; ++r)
        red[wave][kgrp * 4 + r][rowl] = USE_E ? (256.f * acc1[r] + acc2[r])
                                              : (acc1[r] + acc2[r]);
    __syncthreads();
    int nn = tid & 15;
    if (nn < 8) {
        for (int mm = tid >> 4; mm < 16; mm += 8) {
            float s2 = red[0][mm][nn] + red[0][mm][nn + 8]
                     + red[1][mm][nn] + red[1][mm][nn + 8];
            if (USE_E) s2 *= S[p * 16 + mm];
            P[((size_t)(p * 8 + si) * 16 + mm) * 8 + nn] = s2;
        }
    }
}

__global__ __launch_bounds__(256) void combine_kernel(
    const float* __restrict__ P,
    const float* __restrict__ Tcur,
    float* __restrict__ Tnxt,
    unsigned short* __restrict__ TTn,
    const float* __restrict__ Bmat,
    const float* __restrict__ xs,
    const float* __restrict__ ts,
    const float* __restrict__ mread,
    float* __restrict__ mwrite,
    float* __restrict__ ys,
    int s, int do_matvec, int do_mlp)
{
    int tid = threadIdx.x;
    if ((int)blockIdx.x < 199) {
        if (!do_matvec) return;
        __shared__ float u[17][8];
        if (tid < 136) {
            int b = tid & 7;
            int j = tid >> 3;
            float tc = ts[b * TSTEPS + s];
            float tp = (s == 0) ? -ts[b * TSTEPS + 1] : ts[b * TSTEPS + s - 1];
            float val;
            if (j == 0) val = tc - tp;
            else {
                int d = j - 1;
                float xp = (s < 2) ? xs[(b * TSTEPS) * NDATA + d] : mread[b * NDATA + d];
                val = xs[(b * TSTEPS + s) * NDATA + d] - xp;
            }
            u[j][b] = val;
        }
        __syncthreads();
        int idx = blockIdx.x * 256 + tid;
        int r = idx >> 3;
        int n = idx & 7;
        int pp = r >> 4, mm = r & 15;
        const float* Pb = P + ((size_t)pp * 8) * 128 + mm * 8 + n;
        float sum = 0.f;
#pragma unroll
        for (int si = 0; si < KSPLIT; ++si) sum += Pb[si * 128];
        float val = Tcur[r * 8 + n] + sum;
        const float* Brow = Bmat + r * 17;
#pragma unroll
        for (int j = 0; j < 17; ++j) val += Brow[j] * u[j][n];
        Tnxt[r * 8 + n] = val;
        unsigned short hb = f2bf(val);
        TTn[n * LATENT + r] = hb;
        TTn[(n + 8) * LATENT + r] = f2bf(val - bf2f(hb));
    } else {
        if (!do_mlp) return;
        int w = tid >> 6, lane = tid & 63;
        for (int it = 0; it < 2; ++it)
            mlp_batch(Tcur, ts, mwrite, ys, s - 1, w * 2 + it, lane);
    }
}

extern "C" void kernel_launch(void* const* d_in, const int* in_sizes, int n_in,
                              void* d_out, int out_size, void* d_ws, size_t ws_size,
                              hipStream_t stream) {
    const float* xs  = (const float*)d_in[0];
    const float* ts  = (const float*)d_in[1];
    const float* A   = (const float*)d_in[2];
    const float* Bm  = (const float*)d_in[3];
    const float* th0 = (const float*)d_in[4];
    float* ys = (float*)d_out;

    char* ws = (char*)d_ws;
    size_t off = 0;
    auto alloc = [&](size_t bytes) {
        void* p = ws + off;
        off += (bytes + 255) & ~(size_t)255;
        return p;
    };
    float* T0 = (float*)alloc((size_t)LATENT * 8 * sizeof(float));
    float* T1 = (float*)alloc((size_t)LATENT * 8 * sizeof(float));
    unsigned short* TTA = (unsigned short*)alloc((size_t)16 * LATENT * 2);
    unsigned short* TTB = (unsigned short*)alloc((size_t)16 * LATENT * 2);
    float* mb = (float*)alloc(2 * 8 * 16 * sizeof(float));
    float* P  = (float*)alloc((size_t)NTILE * 128 * sizeof(float));
    float* S  = (float*)alloc((size_t)LATENT * sizeof(float));
    unsigned* bar = (unsigned*)alloc(8192);
    unsigned* grpCnt   = bar;             // 16 lines x 128B
    unsigned* superCnt = bar + 512;       // own line
    unsigned* gEpoch   = bar + 544;       // 16 lines x 128B
    size_t Ebytes = (size_t)NPANEL * NCHUNK * 512 * 2;   // int16 fragment-linear: 81 MB
    bool useE = (off + Ebytes + 512) <= ws_size;
    short* Eq = nullptr;
    if (useE) {
        Eq = (short*)alloc(Ebytes);
        row_scale<<<dim3(LATENT), dim3(64), 0, stream>>>(A, S);
        int nthr = LATENT * KBLK;         // NOT divisible by 256: ceil + guard
        convert_Eq<<<dim3((nthr + 255) / 256), dim3(256), 0, stream>>>(A, S, Eq, nthr);
    }
    init_theta<<<dim3((LATENT + 255) / 256), dim3(256), 0, stream>>>(th0, T0, TTA);

    hipError_t coop = hipErrorUnknown;
    if (useE) {
        hipMemsetAsync(bar, 0, 8192, stream);
        void* kargs[] = {
            (void*)&Eq, (void*)&S, (void*)&T0, (void*)&T1,
            (void*)&TTA, (void*)&TTB, (void*)&mb, (void*)&Bm, (void*)&xs,
            (void*)&ts, (void*)&ys, (void*)&grpCnt, (void*)&superCnt, (void*)&gEpoch };
        coop = hipLaunchCooperativeKernel((void*)persistent7,
                                          dim3(200), dim3(1024), kargs, 0, stream);
    }
    if (coop != hipSuccess) {
        // fallback: multi-launch path
        float* T[2] = {T0, T1};
        unsigned short* TT[2] = {TTA, TTB};
        for (int s = 0; s <= TSTEPS; ++s) {
            int cur = s & 1, nxt = cur ^ 1;
            float* mwrite = mb + (s & 1) * 128;
            float* mread  = mb + ((s & 1) ^ 1) * 128;
            int dmv = (s < TSTEPS) ? 1 : 0;
            int dml = (s >= 1) ? 1 : 0;
            if (dmv) {
                if (useE)
                    partial_kernel<true><<<dim3(NTILE), dim3(128), 0, stream>>>(
                        Eq, S, A, TT[cur], P);
                else
                    partial_kernel<false><<<dim3(NTILE), dim3(128), 0, stream>>>(
                        Eq, S, A, TT[cur], P);
            }
            combine_kernel<<<dim3(200), dim3(256), 0, stream>>>(
                P, T[cur], T[nxt], TT[nxt],
                Bm, xs, ts, mread, mwrite, ys, s, dmv, dml);
        }
    }
    (void)in_sizes; (void)n_in; (void)out_size;
}

// Round 14
// 2448.237 us; speedup vs baseline: 1.0488x; 1.0324x over previous
//
#include <hip/hip_runtime.h>
#include <hip/hip_bf16.h>
#include <cmath>

#define LATENT 6368
#define TSTEPS 64
#define NDATA 16
#define NPANEL 398   /* LATENT/16 */
#define KSPLIT 8
#define NCHUNK 199   /* LATENT/32 */
#define CPS 25       /* ceil(199/8) (fallback) */
#define NTILE (NPANEL*KSPLIT)
#define KBLK 796     /* LATENT/8 */
#define AGENT __HIP_MEMORY_SCOPE_AGENT

typedef __attribute__((ext_vector_type(8))) short short8v;
typedef __attribute__((ext_vector_type(4))) float floatx4;

__device__ __forceinline__ unsigned short f2bf(float x) {
    union { float f; unsigned u; } c; c.f = x;
    unsigned r = (c.u + 0x7FFFu + ((c.u >> 16) & 1u)) >> 16;
    return (unsigned short)r;
}
__device__ __forceinline__ float bf2f(unsigned short h) {
    union { unsigned u; float f; } c; c.u = ((unsigned)h) << 16; return c.f;
}

// ---- agent-coherent (sc1) accessors for cross-block mutable data ----
__device__ __forceinline__ unsigned long long ld64c(const void* p) {
    return __hip_atomic_load((const unsigned long long*)p, __ATOMIC_RELAXED, AGENT);
}
__device__ __forceinline__ short8v ldT16c(const unsigned short* p) {
    union { short8v v; unsigned long long q[2]; } r;
    r.q[0] = ld64c(p);
    r.q[1] = ld64c(p + 4);
    return r.v;
}
__device__ __forceinline__ float ldfc(const float* p) {
    return __hip_atomic_load(p, __ATOMIC_RELAXED, AGENT);
}
__device__ __forceinline__ void stfc(float* p, float v) {
    __hip_atomic_store(p, v, __ATOMIC_RELAXED, AGENT);
}
__device__ __forceinline__ void stu16c(unsigned short* p, unsigned short v) {
    __hip_atomic_store(p, v, __ATOMIC_RELAXED, AGENT);
}

// ---------- pass 1: per-row scale S[r] = max|E_row|/32767 ----------
__global__ __launch_bounds__(64) void row_scale(const float* __restrict__ A,
                                                float* __restrict__ S) {
    int row = blockIdx.x;
    int lane = threadIdx.x;
    const float* Ar = A + (size_t)row * LATENT;
    float m = 0.f;
    for (int i = 0; i < 25; ++i) {
        int idx = i * 256 + lane * 4;
        if (idx + 4 <= LATENT) {
            float4 v = *reinterpret_cast<const float4*>(Ar + idx);
            float a0 = v.x - (idx + 0 == row ? 1.f : 0.f);
            float a1 = v.y - (idx + 1 == row ? 1.f : 0.f);
            float a2 = v.z - (idx + 2 == row ? 1.f : 0.f);
            float a3 = v.w - (idx + 3 == row ? 1.f : 0.f);
            m = fmaxf(m, fmaxf(fmaxf(fabsf(a0), fabsf(a1)), fmaxf(fabsf(a2), fabsf(a3))));
        }
    }
#pragma unroll
    for (int o = 32; o; o >>= 1) m = fmaxf(m, __shfl_xor(m, o, 64));
    if (lane == 0) S[row] = fmaxf(m, 1e-30f) * (1.0f / 32767.0f);
}

// ---------- pass 2: quantize E to int16, fragment-linear ----------
__global__ __launch_bounds__(256) void convert_Eq(const float* __restrict__ A,
                                                  const float* __restrict__ S,
                                                  short* __restrict__ Eq,
                                                  int total) {
    int t = blockIdx.x * 256 + threadIdx.x;
    if (t >= total) return;                    // LATENT*KBLK % 256 != 0 (R7 lesson)
    int row = t / KBLK;
    int kb  = t - row * KBLK;
    const float4* src = reinterpret_cast<const float4*>(A + (size_t)row * LATENT + kb * 8);
    float4 v0 = src[0];
    float4 v1 = src[1];
    float v[8] = {v0.x, v0.y, v0.z, v0.w, v1.x, v1.y, v1.z, v1.w};
    int jd = row - kb * 8;
    if (jd >= 0 && jd < 8) v[jd] -= 1.0f;
    float inv = 1.0f / S[row];
    union { short8v s; short q[8]; } o;
#pragma unroll
    for (int j = 0; j < 8; ++j) {
        float qf = rintf(v[j] * inv);
        qf = fminf(fmaxf(qf, -32767.f), 32767.f);
        o.q[j] = (short)qf;
    }
    int p = row >> 4, rowl = row & 15, c = kb >> 2, kgrp = kb & 3;
    int lane = kgrp * 16 + rowl;
    *reinterpret_cast<short8v*>(Eq + ((size_t)(p * NCHUNK + c)) * 512 + lane * 8) = o.s;
}

// ---------- fragment-linear packed theta^T ----------
// TTf[c*512 + (kgrp*16 + slot)*8 + j] = slot<8 ? bf16hi(theta[c*32+kgrp*8+j] batch slot)
//                                              : bf16lo(... batch slot-8)
// A wave (lane = kgrp*16+slot) reads a CONTIGUOUS 1KB per chunk -> 8 lanes per 64B line.
__global__ __launch_bounds__(256) void init_theta(const float* __restrict__ th0,
                                                  float* __restrict__ T0,
                                                  unsigned short* __restrict__ TTf) {
    int r = blockIdx.x * blockDim.x + threadIdx.x;
    if (r >= LATENT) return;
    float v = th0[r];
#pragma unroll
    for (int b = 0; b < 8; ++b) T0[r * 8 + b] = v;
    unsigned short hb = f2bf(v);
    unsigned short lb = f2bf(v - bf2f(hb));
    int c = r >> 5, kg = (r & 31) >> 3, j = r & 7;
    size_t base = (size_t)c * 512 + kg * 128;
#pragma unroll
    for (int n = 0; n < 8; ++n) {
        stu16c(&TTf[base + n * 8 + j], hb);
        stu16c(&TTf[base + (n + 8) * 8 + j], lb);
    }
}

// ---------- wave-local MLP (plain loads; fallback path only) ----------
__device__ void mlp_batch(const float* __restrict__ Tcur, const float* __restrict__ ts,
                          float* __restrict__ mwrite, float* __restrict__ ys,
                          int i, int b, int lane) {
    float tc = ts[b * TSTEPS + i];
    float tp = (i == 0) ? -ts[b * TSTEPS + 1] : ts[b * TSTEPS + i - 1];
    float rin = 2.f * tc - tp;
    float h0 = fmaxf(Tcur[(size_t)lane * 8 + b] * rin + Tcur[(size_t)(64 + lane) * 8 + b], 0.f);
    float h1 = Tcur[(size_t)(4224 + lane) * 8 + b];
#pragma unroll 8
    for (int k = 0; k < 64; ++k)
        h1 += Tcur[(size_t)(128 + lane * 64 + k) * 8 + b] * __shfl(h0, k, 64);
    h1 = fmaxf(h1, 0.f);
    float o = 0.f;
    if (lane < 32) o = Tcur[(size_t)(6336 + lane) * 8 + b];
#pragma unroll 8
    for (int k = 0; k < 64; ++k) {
        float hk = __shfl(h1, k, 64);
        if (lane < 32) o += Tcur[(size_t)(4288 + lane * 64 + k) * 8 + b] * hk;
    }
    if (lane < 32) {
        float z = tanhf(o);
        float res;
        if (lane < 16) { res = z; mwrite[b * NDATA + lane] = z; }
        else           { res = log1pf(expf(z)); }
        ys[(size_t)b * (TSTEPS * 32) + (size_t)i * 32 + lane] = res;
    }
}

// ---------- wave-local MLP, coherent loads (persistent path) ----------
__device__ void mlp_batch_coh(const float* __restrict__ Tcur, const float* __restrict__ ts,
                              float* __restrict__ mwrite, float* __restrict__ ys,
                              int i, int b, int lane) {
    float tc = ts[b * TSTEPS + i];
    float tp = (i == 0) ? -ts[b * TSTEPS + 1] : ts[b * TSTEPS + i - 1];
    float rin = 2.f * tc - tp;
    float h0 = fmaxf(ldfc(&Tcur[(size_t)lane * 8 + b]) * rin
                     + ldfc(&Tcur[(size_t)(64 + lane) * 8 + b]), 0.f);
    float h1 = ldfc(&Tcur[(size_t)(4224 + lane) * 8 + b]);
#pragma unroll 8
    for (int k = 0; k < 64; ++k)
        h1 += ldfc(&Tcur[(size_t)(128 + lane * 64 + k) * 8 + b]) * __shfl(h0, k, 64);
    h1 = fmaxf(h1, 0.f);
    float o = 0.f;
    if (lane < 32) o = ldfc(&Tcur[(size_t)(6336 + lane) * 8 + b]);
#pragma unroll 8
    for (int k = 0; k < 64; ++k) {
        float hk = __shfl(h1, k, 64);
        if (lane < 32) o += ldfc(&Tcur[(size_t)(4288 + lane * 64 + k) * 8 + b]) * hk;
    }
    if (lane < 32) {
        float z = tanhf(o);
        float res;
        if (lane < 16) { res = z; stfc(&mwrite[b * NDATA + lane], z); }
        else           { res = log1pf(expf(z)); }
        ys[(size_t)b * (TSTEPS * 32) + (size_t)i * 32 + lane] = res;
    }
}

// ---------- grid barrier: fence-free (vmcnt drain + relaxed counters) ----------
__device__ __forceinline__ void gsync2(unsigned* grpCnt, unsigned* superCnt,
                                       unsigned* gEpoch, unsigned iter) {
    asm volatile("s_waitcnt vmcnt(0)" ::: "memory");
    __syncthreads();
    if (threadIdx.x == 0) {
        unsigned g = blockIdx.x & 15u;
        unsigned gsz = (g < 8u) ? 13u : 12u;
        unsigned v = __hip_atomic_fetch_add(&grpCnt[g * 32], 1u, __ATOMIC_RELAXED, AGENT);
        if (v == iter * gsz - 1u) {
            unsigned w = __hip_atomic_fetch_add(superCnt, 1u, __ATOMIC_RELAXED, AGENT);
            if (w == iter * 16u - 1u) {
#pragma unroll
                for (int i2 = 0; i2 < 16; ++i2)
                    __hip_atomic_store(&gEpoch[i2 * 32], iter, __ATOMIC_RELAXED, AGENT);
            }
        }
        while (__hip_atomic_load(&gEpoch[g * 32], __ATOMIC_RELAXED, AGENT) < iter)
            __builtin_amdgcn_s_sleep(4);
    }
    __syncthreads();
}

// exact int16 -> bf16(hi8)*256 + bf16(lo8); 2 panels share one theta fragment
#define COMP2(EA, EB, TP) do {                                                    \
    union { short8v sv; unsigned short us[8]; } HA, LA, HB, LB;                   \
    _Pragma("unroll")                                                             \
    for (int j = 0; j < 8; ++j) {                                                 \
        int qa = (EA)[j], qb = (EB)[j];                                           \
        union { float f; unsigned u; } x0, x1, x2, x3;                            \
        x0.f = (float)(qa >> 8);  HA.us[j] = (unsigned short)(x0.u >> 16);        \
        x1.f = (float)(qa & 255); LA.us[j] = (unsigned short)(x1.u >> 16);        \
        x2.f = (float)(qb >> 8);  HB.us[j] = (unsigned short)(x2.u >> 16);        \
        x3.f = (float)(qb & 255); LB.us[j] = (unsigned short)(x3.u >> 16);        \
    }                                                                             \
    acc1A = __builtin_amdgcn_mfma_f32_16x16x32_bf16(HA.sv, (TP), acc1A, 0, 0, 0); \
    acc2A = __builtin_amdgcn_mfma_f32_16x16x32_bf16(LA.sv, (TP), acc2A, 0, 0, 0); \
    acc1B = __builtin_amdgcn_mfma_f32_16x16x32_bf16(HB.sv, (TP), acc1B, 0, 0, 0); \
    acc2B = __builtin_amdgcn_mfma_f32_16x16x32_bf16(LB.sv, (TP), acc2B, 0, 0, 0); \
} while (0)

#define LDE(P)  (*reinterpret_cast<const short8v*>(P))

// ---------- persistent v8: fragment-linear theta (coalesced 1KB/chunk wave reads),
// ---------- 199 blocks x 2 panels, fence-free barrier ----------
__global__ __launch_bounds__(1024, 4) void persistent8(
    const short* __restrict__ Eq, const float* __restrict__ S,
    float* __restrict__ T0buf, float* __restrict__ T1buf,
    unsigned short* __restrict__ TTA, unsigned short* __restrict__ TTB,
    float* __restrict__ mb,
    const float* __restrict__ Bmat, const float* __restrict__ xs,
    const float* __restrict__ ts, float* __restrict__ ys,
    unsigned* grpCnt, unsigned* superCnt, unsigned* gEpoch)
{
    __shared__ float red[16][2][16][16];
    __shared__ float ush[17][8];
    int tid = threadIdx.x, blk = blockIdx.x;
    int wave = tid >> 6, lane = tid & 63;
    int rowl = lane & 15, kgrp = lane >> 4;
    // 199 chunks over 16 waves: waves 0..6 get 13, waves 7..15 get 12
    int cs = (wave < 7) ? wave * 13 : 91 + (wave - 7) * 12;
    int nch = (wave < 7) ? 13 : 12;
    int panelA = blk * 2;
    unsigned iter = 0;
    for (int s = 0; s < TSTEPS; ++s) {
        const float* Tc = (s & 1) ? T1buf : T0buf;
        float* Tn       = (s & 1) ? T0buf : T1buf;
        const unsigned short* TTc = (s & 1) ? TTB : TTA;
        unsigned short* TTn       = (s & 1) ? TTA : TTB;
        float* mwrite = mb + (s & 1) * 128;
        const float* mread = mb + ((s & 1) ^ 1) * 128;
        if (blk < 199) {
            if (tid < 136) {
                int b = tid & 7, j = tid >> 3;
                float tc = ts[b * TSTEPS + s];
                float tp = (s == 0) ? -ts[b * TSTEPS + 1] : ts[b * TSTEPS + s - 1];
                float val;
                if (j == 0) val = tc - tp;
                else {
                    int d = j - 1;
                    float xp = (s < 2) ? xs[(b * TSTEPS) * NDATA + d]
                                       : ldfc(&mread[b * NDATA + d]);
                    val = xs[(b * TSTEPS + s) * NDATA + d] - xp;
                }
                ush[j][b] = val;
            }
            floatx4 acc1A = {0.f,0.f,0.f,0.f}, acc2A = {0.f,0.f,0.f,0.f};
            floatx4 acc1B = {0.f,0.f,0.f,0.f}, acc2B = {0.f,0.f,0.f,0.f};
            const short* epA = Eq + ((size_t)(panelA * NCHUNK + cs)) * 512 + lane * 8;
            const short* epB = epA + (size_t)NCHUNK * 512;
            const unsigned short* tq = TTc + (size_t)cs * 512 + lane * 8;   // contiguous!
            short8v a0 = LDE(epA),        a1 = LDE(epA + 512),
                    a2 = LDE(epA + 1024), a3 = LDE(epA + 1536);
            short8v b0 = LDE(epB),        b1 = LDE(epB + 512),
                    b2 = LDE(epB + 1024), b3 = LDE(epB + 1536);
            short8v t0 = ldT16c(tq),        t1 = ldT16c(tq + 512),
                    t2 = ldT16c(tq + 1024), t3 = ldT16c(tq + 1536);
            int c = 0;
            for (; c + 8 <= nch; c += 4) {
                COMP2(a0, b0, t0); a0 = LDE(epA + 2048); b0 = LDE(epB + 2048); t0 = ldT16c(tq + 2048);
                COMP2(a1, b1, t1); a1 = LDE(epA + 2560); b1 = LDE(epB + 2560); t1 = ldT16c(tq + 2560);
                COMP2(a2, b2, t2); a2 = LDE(epA + 3072); b2 = LDE(epB + 3072); t2 = ldT16c(tq + 3072);
                COMP2(a3, b3, t3); a3 = LDE(epA + 3584); b3 = LDE(epB + 3584); t3 = ldT16c(tq + 3584);
                epA += 2048; epB += 2048; tq += 2048;
            }
            COMP2(a0, b0, t0); COMP2(a1, b1, t1); COMP2(a2, b2, t2); COMP2(a3, b3, t3);
            for (int k2 = 4; c + k2 < nch; ++k2) {
                a0 = LDE(epA + k2 * 512); b0 = LDE(epB + k2 * 512); t0 = ldT16c(tq + k2 * 512);
                COMP2(a0, b0, t0);
            }
            // C/D: col(lane&15)=batch-slot, row(kgrp*4+r)=output row
#pragma unroll
            for (int r = 0; r < 4; ++r) {
                red[wave][0][kgrp * 4 + r][rowl] = 256.f * acc1A[r] + acc2A[r];
                red[wave][1][kgrp * 4 + r][rowl] = 256.f * acc1B[r] + acc2B[r];
            }
            __syncthreads();
            if (tid < 256) {
                int m32 = tid >> 3, n = tid & 7;
                int ph = m32 >> 4, m = m32 & 15;
                float sum = 0.f;
#pragma unroll
                for (int w = 0; w < 16; ++w)
                    sum += red[w][ph][m][n] + red[w][ph][m][n + 8];
                int r = blk * 32 + m32;
                float val = ldfc(&Tc[r * 8 + n]) + S[r] * sum;
                const float* Brow = Bmat + r * 17;
#pragma unroll
                for (int j = 0; j < 17; ++j) val += Brow[j] * ush[j][n];
                stfc(&Tn[r * 8 + n], val);
                unsigned short hb = f2bf(val);
                // fragment-linear theta write: this block owns chunk c = r>>5 = blk
                int kg = m32 >> 3, j2 = m32 & 7;
                size_t tb = (size_t)blk * 512 + kg * 128;
                stu16c(&TTn[tb + n * 8 + j2], hb);
                stu16c(&TTn[tb + (n + 8) * 8 + j2], f2bf(val - bf2f(hb)));
            }
        } else {
            if (s >= 1 && wave < 8)
                mlp_batch_coh(Tc, ts, mwrite, ys, s - 1, wave, lane);
        }
        ++iter; gsync2(grpCnt, superCnt, gEpoch, iter);
    }
    if (blk == 199 && wave < 8)
        mlp_batch_coh(T0buf, ts, mb, ys, TSTEPS - 1, wave, lane);
}

// ---------- fallback path (multi-launch, int16 E, fragment-linear theta) ----------
template<bool USE_E>
__global__ __launch_bounds__(128) void partial_kernel(
    const short* __restrict__ Eq, const float* __restrict__ S,
    const float* __restrict__ Af,
    const unsigned short* __restrict__ TTc,
    float* __restrict__ P)
{
    int blk = blockIdx.x;
    int p  = blk >> 3;
    int si = blk & 7;
    int tid = threadIdx.x;
    int wave = tid >> 6;
    int lane = tid & 63;
    int rowl = lane & 15;
    int kgrp = lane >> 4;
    int row = p * 16 + rowl;
    int c0 = si * CPS;
    int c1 = c0 + CPS; if (c1 > NCHUNK) c1 = NCHUNK;
    int nch = c1 - c0;
    int half = (nch + 1) >> 1;
    int csw = c0 + wave * half;
    int cew = csw + half; if (cew > c1) cew = c1;
    floatx4 acc1 = {0.f, 0.f, 0.f, 0.f};
    floatx4 acc2 = {0.f, 0.f, 0.f, 0.f};
    for (int c = csw; c < cew; ++c) {
        int k = c * 32 + kgrp * 8;
        short8v ehf, elf;
        if (USE_E) {
            short8v ev = *reinterpret_cast<const short8v*>(
                Eq + ((size_t)(p * NCHUNK + c)) * 512 + lane * 8);
            union { short8v sv; unsigned short us[8]; } EH, EL;
#pragma unroll
            for (int j = 0; j < 8; ++j) {
                int q = ev[j];
                union { float f; unsigned u; } ch2, cl2;
                ch2.f = (float)(q >> 8);
                cl2.f = (float)(q & 255);
                EH.us[j] = (unsigned short)(ch2.u >> 16);
                EL.us[j] = (unsigned short)(cl2.u >> 16);
            }
            ehf = EH.sv; elf = EL.sv;
        } else {
            const float* ap = Af + (size_t)row * LATENT + k;
            float v[8];
#pragma unroll
            for (int j = 0; j < 8; ++j) v[j] = ap[j];
            int jd = row - k;
            if (jd >= 0 && jd < 8) v[jd] -= 1.0f;
            union { short8v sv; unsigned short us[8]; } ch, cl;
#pragma unroll
            for (int j = 0; j < 8; ++j) {
                unsigned short hb = f2bf(v[j]);
                ch.us[j] = hb;
                cl.us[j] = f2bf(v[j] - bf2f(hb));
            }
            ehf = ch.sv; elf = cl.sv;
        }
        short8v tpf = *reinterpret_cast<const short8v*>(TTc + (size_t)c * 512 + lane * 8);
        acc1 = __builtin_amdgcn_mfma_f32_16x16x32_bf16(ehf, tpf, acc1, 0, 0, 0);
        acc2 = __builtin_amdgcn_mfma_f32_16x16x32_bf16(elf, tpf, acc2, 0, 0, 0);
    }
    __shared__ float red[2][16][16];
#pragma unroll
    for (int r = 0; r < 4; ++r)
        red[wave][kgrp * 4 + r][rowl] = USE_E ? (256.f * acc1[r] + acc2[r])
                                              : (acc1[r] + acc2[r]);
    __syncthreads();
    int nn = tid & 15;
    if (nn < 8) {
        for (int mm = tid >> 4; mm < 16; mm += 8) {
            float s2 = red[0][mm][nn] + red[0][mm][nn + 8]
                     + red[1][mm][nn] + red[1][mm][nn + 8];
            if (USE_E) s2 *= S[p * 16 + mm];
            P[((size_t)(p * 8 + si) * 16 + mm) * 8 + nn] = s2;
        }
    }
}

__global__ __launch_bounds__(256) void combine_kernel(
    const float* __restrict__ P,
    const float* __restrict__ Tcur,
    float* __restrict__ Tnxt,
    unsigned short* __restrict__ TTn,
    const float* __restrict__ Bmat,
    const float* __restrict__ xs,
    const float* __restrict__ ts,
    const float* __restrict__ mread,
    float* __restrict__ mwrite,
    float* __restrict__ ys,
    int s, int do_matvec, int do_mlp)
{
    int tid = threadIdx.x;
    if ((int)blockIdx.x < 199) {
        if (!do_matvec) return;
        __shared__ float u[17][8];
        if (tid < 136) {
            int b = tid & 7;
            int j = tid >> 3;
            float tc = ts[b * TSTEPS + s];
            float tp = (s == 0) ? -ts[b * TSTEPS + 1] : ts[b * TSTEPS + s - 1];
            float val;
            if (j == 0) val = tc - tp;
            else {
                int d = j - 1;
                float xp = (s < 2) ? xs[(b * TSTEPS) * NDATA + d] : mread[b * NDATA + d];
                val = xs[(b * TSTEPS + s) * NDATA + d] - xp;
            }
            u[j][b] = val;
        }
        __syncthreads();
        int idx = blockIdx.x * 256 + tid;
        int r = idx >> 3;
        int n = idx & 7;
        int pp = r >> 4, mm = r & 15;
        const float* Pb = P + ((size_t)pp * 8) * 128 + mm * 8 + n;
        float sum = 0.f;
#pragma unroll
        for (int si = 0; si < KSPLIT; ++si) sum += Pb[si * 128];
        float val = Tcur[r * 8 + n] + sum;
        const float* Brow = Bmat + r * 17;
#pragma unroll
        for (int j = 0; j < 17; ++j) val += Brow[j] * u[j][n];
        Tnxt[r * 8 + n] = val;
        unsigned short hb = f2bf(val);
        int c2 = r >> 5, kg = (r & 31) >> 3, j2 = r & 7;
        size_t tb = (size_t)c2 * 512 + kg * 128;
        TTn[tb + n * 8 + j2] = hb;
        TTn[tb + (n + 8) * 8 + j2] = f2bf(val - bf2f(hb));
    } else {
        if (!do_mlp) return;
        int w = tid >> 6, lane = tid & 63;
        for (int it = 0; it < 2; ++it)
            mlp_batch(Tcur, ts, mwrite, ys, s - 1, w * 2 + it, lane);
    }
}

extern "C" void kernel_launch(void* const* d_in, const int* in_sizes, int n_in,
                              void* d_out, int out_size, void* d_ws, size_t ws_size,
                              hipStream_t stream) {
    const float* xs  = (const float*)d_in[0];
    const float* ts  = (const float*)d_in[1];
    const float* A   = (const float*)d_in[2];
    const float* Bm  = (const float*)d_in[3];
    const float* th0 = (const float*)d_in[4];
    float* ys = (float*)d_out;

    char* ws = (char*)d_ws;
    size_t off = 0;
    auto alloc = [&](size_t bytes) {
        void* p = ws + off;
        off += (bytes + 255) & ~(size_t)255;
        return p;
    };
    float* T0 = (float*)alloc((size_t)LATENT * 8 * sizeof(float));
    float* T1 = (float*)alloc((size_t)LATENT * 8 * sizeof(float));
    unsigned short* TTA = (unsigned short*)alloc((size_t)16 * LATENT * 2);
    unsigned short* TTB = (unsigned short*)alloc((size_t)16 * LATENT * 2);
    float* mb = (float*)alloc(2 * 8 * 16 * sizeof(float));
    float* P  = (float*)alloc((size_t)NTILE * 128 * sizeof(float));
    float* S  = (float*)alloc((size_t)LATENT * sizeof(float));
    unsigned* bar = (unsigned*)alloc(8192);
    unsigned* grpCnt   = bar;             // 16 lines x 128B
    unsigned* superCnt = bar + 512;       // own line
    unsigned* gEpoch   = bar + 544;       // 16 lines x 128B
    size_t Ebytes = (size_t)NPANEL * NCHUNK * 512 * 2;   // int16 fragment-linear: 81 MB
    bool useE = (off + Ebytes + 512) <= ws_size;
    short* Eq = nullptr;
    if (useE) {
        Eq = (short*)alloc(Ebytes);
        row_scale<<<dim3(LATENT), dim3(64), 0, stream>>>(A, S);
        int nthr = LATENT * KBLK;         // NOT divisible by 256: ceil + guard
        convert_Eq<<<dim3((nthr + 255) / 256), dim3(256), 0, stream>>>(A, S, Eq, nthr);
    }
    init_theta<<<dim3((LATENT + 255) / 256), dim3(256), 0, stream>>>(th0, T0, TTA);

    hipError_t coop = hipErrorUnknown;
    if (useE) {
        hipMemsetAsync(bar, 0, 8192, stream);
        void* kargs[] = {
            (void*)&Eq, (void*)&S, (void*)&T0, (void*)&T1,
            (void*)&TTA, (void*)&TTB, (void*)&mb, (void*)&Bm, (void*)&xs,
            (void*)&ts, (void*)&ys, (void*)&grpCnt, (void*)&superCnt, (void*)&gEpoch };
        coop = hipLaunchCooperativeKernel((void*)persistent8,
                                          dim3(200), dim3(1024), kargs, 0, stream);
    }
    if (coop != hipSuccess) {
        // fallback: multi-launch path
        float* T[2] = {T0, T1};
        unsigned short* TT[2] = {TTA, TTB};
        for (int s = 0; s <= TSTEPS; ++s) {
            int cur = s & 1, nxt = cur ^ 1;
            float* mwrite = mb + (s & 1) * 128;
            float* mread  = mb + ((s & 1) ^ 1) * 128;
            int dmv = (s < TSTEPS) ? 1 : 0;
            int dml = (s >= 1) ? 1 : 0;
            if (dmv) {
                if (useE)
                    partial_kernel<true><<<dim3(NTILE), dim3(128), 0, stream>>>(
                        Eq, S, A, TT[cur], P);
                else
                    partial_kernel<false><<<dim3(NTILE), dim3(128), 0, stream>>>(
                        Eq, S, A, TT[cur], P);
            }
            combine_kernel<<<dim3(200), dim3(256), 0, stream>>>(
                P, T[cur], T[nxt], TT[nxt],
                Bm, xs, ts, mread, mwrite, ys, s, dmv, dml);
        }
    }
    (void)in_sizes; (void)n_in; (void)out_size;
}

// Round 15
// 2384.090 us; speedup vs baseline: 1.0770x; 1.0269x over previous
//
#include <hip/hip_runtime.h>
#include <hip/hip_bf16.h>
#include <cmath>

#define LATENT 6368
#define TSTEPS 64
#define NDATA 16
#define NPANEL 398   /* LATENT/16 */
#define KSPLIT 8
#define NCHUNK 199   /* LATENT/32 */
#define CPS 25       /* ceil(199/8) (fallback) */
#define NTILE (NPANEL*KSPLIT)
#define KBLK 796     /* LATENT/8 */
#define AGENT __HIP_MEMORY_SCOPE_AGENT
#define TSTR  51200   /* floats per T slot (204800 B) */
#define TTSTR 102400  /* shorts per TT slot (204800 B) */

typedef __attribute__((ext_vector_type(8))) short short8v;
typedef __attribute__((ext_vector_type(4))) float floatx4;

__device__ __forceinline__ unsigned short f2bf(float x) {
    union { float f; unsigned u; } c; c.f = x;
    unsigned r = (c.u + 0x7FFFu + ((c.u >> 16) & 1u)) >> 16;
    return (unsigned short)r;
}
__device__ __forceinline__ float bf2f(unsigned short h) {
    union { unsigned u; float f; } c; c.u = ((unsigned)h) << 16; return c.f;
}

// ---- sc1 (agent write-through) stores for cross-block mutable data ----
__device__ __forceinline__ void stfc(float* p, float v) {
    __hip_atomic_store(p, v, __ATOMIC_RELAXED, AGENT);
}
__device__ __forceinline__ void stu16c(unsigned short* p, unsigned short v) {
    __hip_atomic_store(p, v, __ATOMIC_RELAXED, AGENT);
}

// ---------- pass 1: per-row scale S[r] = max|E_row|/32767 ----------
__global__ __launch_bounds__(64) void row_scale(const float* __restrict__ A,
                                                float* __restrict__ S) {
    int row = blockIdx.x;
    int lane = threadIdx.x;
    const float* Ar = A + (size_t)row * LATENT;
    float m = 0.f;
    for (int i = 0; i < 25; ++i) {
        int idx = i * 256 + lane * 4;
        if (idx + 4 <= LATENT) {
            float4 v = *reinterpret_cast<const float4*>(Ar + idx);
            float a0 = v.x - (idx + 0 == row ? 1.f : 0.f);
            float a1 = v.y - (idx + 1 == row ? 1.f : 0.f);
            float a2 = v.z - (idx + 2 == row ? 1.f : 0.f);
            float a3 = v.w - (idx + 3 == row ? 1.f : 0.f);
            m = fmaxf(m, fmaxf(fmaxf(fabsf(a0), fabsf(a1)), fmaxf(fabsf(a2), fabsf(a3))));
        }
    }
#pragma unroll
    for (int o = 32; o; o >>= 1) m = fmaxf(m, __shfl_xor(m, o, 64));
    if (lane == 0) S[row] = fmaxf(m, 1e-30f) * (1.0f / 32767.0f);
}

// ---------- pass 2: quantize E to int16, fragment-linear ----------
__global__ __launch_bounds__(256) void convert_Eq(const float* __restrict__ A,
                                                  const float* __restrict__ S,
                                                  short* __restrict__ Eq,
                                                  int total) {
    int t = blockIdx.x * 256 + threadIdx.x;
    if (t >= total) return;                    // LATENT*KBLK % 256 != 0 (R7 lesson)
    int row = t / KBLK;
    int kb  = t - row * KBLK;
    const float4* src = reinterpret_cast<const float4*>(A + (size_t)row * LATENT + kb * 8);
    float4 v0 = src[0];
    float4 v1 = src[1];
    float v[8] = {v0.x, v0.y, v0.z, v0.w, v1.x, v1.y, v1.z, v1.w};
    int jd = row - kb * 8;
    if (jd >= 0 && jd < 8) v[jd] -= 1.0f;
    float inv = 1.0f / S[row];
    union { short8v s; short q[8]; } o;
#pragma unroll
    for (int j = 0; j < 8; ++j) {
        float qf = rintf(v[j] * inv);
        qf = fminf(fmaxf(qf, -32767.f), 32767.f);
        o.q[j] = (short)qf;
    }
    int p = row >> 4, rowl = row & 15, c = kb >> 2, kgrp = kb & 3;
    int lane = kgrp * 16 + rowl;
    *reinterpret_cast<short8v*>(Eq + ((size_t)(p * NCHUNK + c)) * 512 + lane * 8) = o.s;
}

// ---------- init theta slot 64 (plain stores; kernel-boundary release flushes) ----
// fragment-linear: TT[c*512 + (kg*16+slot)*8 + j], slot<8 = hi batch slot, else lo.
__global__ __launch_bounds__(256) void init_theta(const float* __restrict__ th0,
                                                  float* __restrict__ T0,
                                                  unsigned short* __restrict__ TT0) {
    int r = blockIdx.x * blockDim.x + threadIdx.x;
    if (r >= LATENT) return;
    float v = th0[r];
#pragma unroll
    for (int b = 0; b < 8; ++b) T0[r * 8 + b] = v;
    unsigned short hb = f2bf(v);
    unsigned short lb = f2bf(v - bf2f(hb));
    int c = r >> 5, kg = (r & 31) >> 3, j = r & 7;
    size_t base = (size_t)c * 512 + kg * 128;
#pragma unroll
    for (int n = 0; n < 8; ++n) {
        TT0[base + n * 8 + j] = hb;
        TT0[base + (n + 8) * 8 + j] = lb;
    }
}

// ---------- wave-local MLP, plain loads (rotation makes them coherent); mean via sc1 ----
__device__ void mlp_batch_rot(const float* __restrict__ Tcur, const float* __restrict__ ts,
                              float* __restrict__ mwrite, float* __restrict__ ys,
                              int i, int b, int lane) {
    float tc = ts[b * TSTEPS + i];
    float tp = (i == 0) ? -ts[b * TSTEPS + 1] : ts[b * TSTEPS + i - 1];
    float rin = 2.f * tc - tp;
    float h0 = fmaxf(Tcur[(size_t)lane * 8 + b] * rin + Tcur[(size_t)(64 + lane) * 8 + b], 0.f);
    float h1 = Tcur[(size_t)(4224 + lane) * 8 + b];
#pragma unroll 8
    for (int k = 0; k < 64; ++k)
        h1 += Tcur[(size_t)(128 + lane * 64 + k) * 8 + b] * __shfl(h0, k, 64);
    h1 = fmaxf(h1, 0.f);
    float o = 0.f;
    if (lane < 32) o = Tcur[(size_t)(6336 + lane) * 8 + b];
#pragma unroll 8
    for (int k = 0; k < 64; ++k) {
        float hk = __shfl(h1, k, 64);
        if (lane < 32) o += Tcur[(size_t)(4288 + lane * 64 + k) * 8 + b] * hk;
    }
    if (lane < 32) {
        float z = tanhf(o);
        float res;
        if (lane < 16) { res = z; stfc(&mwrite[b * NDATA + lane], z); }
        else           { res = log1pf(expf(z)); }
        ys[(size_t)b * (TSTEPS * 32) + (size_t)i * 32 + lane] = res;
    }
}

// plain-store variant for the fallback path (kernel-boundary coherence)
__device__ void mlp_batch(const float* __restrict__ Tcur, const float* __restrict__ ts,
                          float* __restrict__ mwrite, float* __restrict__ ys,
                          int i, int b, int lane) {
    float tc = ts[b * TSTEPS + i];
    float tp = (i == 0) ? -ts[b * TSTEPS + 1] : ts[b * TSTEPS + i - 1];
    float rin = 2.f * tc - tp;
    float h0 = fmaxf(Tcur[(size_t)lane * 8 + b] * rin + Tcur[(size_t)(64 + lane) * 8 + b], 0.f);
    float h1 = Tcur[(size_t)(4224 + lane) * 8 + b];
#pragma unroll 8
    for (int k = 0; k < 64; ++k)
        h1 += Tcur[(size_t)(128 + lane * 64 + k) * 8 + b] * __shfl(h0, k, 64);
    h1 = fmaxf(h1, 0.f);
    float o = 0.f;
    if (lane < 32) o = Tcur[(size_t)(6336 + lane) * 8 + b];
#pragma unroll 8
    for (int k = 0; k < 64; ++k) {
        float hk = __shfl(h1, k, 64);
        if (lane < 32) o += Tcur[(size_t)(4288 + lane * 64 + k) * 8 + b] * hk;
    }
    if (lane < 32) {
        float z = tanhf(o);
        float res;
        if (lane < 16) { res = z; mwrite[b * NDATA + lane] = z; }
        else           { res = log1pf(expf(z)); }
        ys[(size_t)b * (TSTEPS * 32) + (size_t)i * 32 + lane] = res;
    }
}

// ---------- grid barrier: fence-free (vmcnt drain + relaxed counters) ----------
__device__ __forceinline__ void gsync2(unsigned* grpCnt, unsigned* superCnt,
                                       unsigned* gEpoch, unsigned iter) {
    asm volatile("s_waitcnt vmcnt(0)" ::: "memory");
    __syncthreads();
    if (threadIdx.x == 0) {
        unsigned g = blockIdx.x & 15u;
        unsigned gsz = (g < 8u) ? 13u : 12u;
        unsigned v = __hip_atomic_fetch_add(&grpCnt[g * 32], 1u, __ATOMIC_RELAXED, AGENT);
        if (v == iter * gsz - 1u) {
            unsigned w = __hip_atomic_fetch_add(superCnt, 1u, __ATOMIC_RELAXED, AGENT);
            if (w == iter * 16u - 1u) {
#pragma unroll
                for (int i2 = 0; i2 < 16; ++i2)
                    __hip_atomic_store(&gEpoch[i2 * 32], iter, __ATOMIC_RELAXED, AGENT);
            }
        }
        while (__hip_atomic_load(&gEpoch[g * 32], __ATOMIC_RELAXED, AGENT) < iter)
            __builtin_amdgcn_s_sleep(4);
    }
    __syncthreads();
}

// exact int16 -> bf16(hi8)*256 + bf16(lo8); 2 panels share one theta fragment
#define COMP2(EA, EB, TP) do {                                                    \
    union { short8v sv; unsigned short us[8]; } HA, LA, HB, LB;                   \
    _Pragma("unroll")                                                             \
    for (int j = 0; j < 8; ++j) {                                                 \
        int qa = (EA)[j], qb = (EB)[j];                                           \
        union { float f; unsigned u; } x0, x1, x2, x3;                            \
        x0.f = (float)(qa >> 8);  HA.us[j] = (unsigned short)(x0.u >> 16);        \
        x1.f = (float)(qa & 255); LA.us[j] = (unsigned short)(x1.u >> 16);        \
        x2.f = (float)(qb >> 8);  HB.us[j] = (unsigned short)(x2.u >> 16);        \
        x3.f = (float)(qb & 255); LB.us[j] = (unsigned short)(x3.u >> 16);        \
    }                                                                             \
    acc1A = __builtin_amdgcn_mfma_f32_16x16x32_bf16(HA.sv, (TP), acc1A, 0, 0, 0); \
    acc2A = __builtin_amdgcn_mfma_f32_16x16x32_bf16(LA.sv, (TP), acc2A, 0, 0, 0); \
    acc1B = __builtin_amdgcn_mfma_f32_16x16x32_bf16(HB.sv, (TP), acc1B, 0, 0, 0); \
    acc2B = __builtin_amdgcn_mfma_f32_16x16x32_bf16(LB.sv, (TP), acc2B, 0, 0, 0); \
} while (0)

#define LDE(P)  (*reinterpret_cast<const short8v*>(P))

// ---------- persistent v9: rotating theta buffers (descending addresses) ->
// ---------- PLAIN CACHED loads everywhere; sc1 only for writes; fence-free barrier --
__global__ __launch_bounds__(1024, 4) void persistent9(
    const short* __restrict__ Eq, const float* __restrict__ S,
    float* __restrict__ Tbase, unsigned short* __restrict__ TTbase,
    float* __restrict__ mbase,
    const float* __restrict__ Bmat, const float* __restrict__ xs,
    const float* __restrict__ ts, float* __restrict__ ys,
    unsigned* grpCnt, unsigned* superCnt, unsigned* gEpoch)
{
    __shared__ float red[16][2][16][16];
    __shared__ float ush[17][8];
    int tid = threadIdx.x, blk = blockIdx.x;
    int wave = tid >> 6, lane = tid & 63;
    int rowl = lane & 15, kgrp = lane >> 4;
    int cs = (wave < 7) ? wave * 13 : 91 + (wave - 7) * 12;
    int nch = (wave < 7) ? 13 : 12;
    int panelA = blk * 2;
    unsigned iter = 0;
    for (int s = 0; s < TSTEPS; ++s) {
        const float* Tc = Tbase + (size_t)(64 - s) * TSTR;
        float* Tn       = Tbase + (size_t)(63 - s) * TSTR;
        const unsigned short* TTc = TTbase + (size_t)(64 - s) * TTSTR;
        unsigned short* TTn       = TTbase + (size_t)(63 - s) * TTSTR;
        float* mwrite = mbase + (size_t)(64 - s) * 128;       // mean_{s-1}, written in step s
        const float* mread = mbase + (size_t)(65 - s) * 128;  // mean_{s-2}, written in step s-1
        if (blk < 199) {
            if (tid < 136) {
                int b = tid & 7, j = tid >> 3;
                float tc = ts[b * TSTEPS + s];
                float tp = (s == 0) ? -ts[b * TSTEPS + 1] : ts[b * TSTEPS + s - 1];
                float val;
                if (j == 0) val = tc - tp;
                else {
                    int d = j - 1;
                    float xp = (s < 2) ? xs[(b * TSTEPS) * NDATA + d]
                                       : mread[b * NDATA + d];
                    val = xs[(b * TSTEPS + s) * NDATA + d] - xp;
                }
                ush[j][b] = val;
            }
            floatx4 acc1A = {0.f,0.f,0.f,0.f}, acc2A = {0.f,0.f,0.f,0.f};
            floatx4 acc1B = {0.f,0.f,0.f,0.f}, acc2B = {0.f,0.f,0.f,0.f};
            const short* epA = Eq + ((size_t)(panelA * NCHUNK + cs)) * 512 + lane * 8;
            const short* epB = epA + (size_t)NCHUNK * 512;
            const unsigned short* tq = TTc + (size_t)cs * 512 + lane * 8;
            short8v a0 = LDE(epA),        a1 = LDE(epA + 512),
                    a2 = LDE(epA + 1024), a3 = LDE(epA + 1536);
            short8v b0 = LDE(epB),        b1 = LDE(epB + 512),
                    b2 = LDE(epB + 1024), b3 = LDE(epB + 1536);
            short8v t0 = LDE(tq),         t1 = LDE(tq + 512),
                    t2 = LDE(tq + 1024),  t3 = LDE(tq + 1536);
            int c = 0;
            for (; c + 8 <= nch; c += 4) {
                COMP2(a0, b0, t0); a0 = LDE(epA + 2048); b0 = LDE(epB + 2048); t0 = LDE(tq + 2048);
                COMP2(a1, b1, t1); a1 = LDE(epA + 2560); b1 = LDE(epB + 2560); t1 = LDE(tq + 2560);
                COMP2(a2, b2, t2); a2 = LDE(epA + 3072); b2 = LDE(epB + 3072); t2 = LDE(tq + 3072);
                COMP2(a3, b3, t3); a3 = LDE(epA + 3584); b3 = LDE(epB + 3584); t3 = LDE(tq + 3584);
                epA += 2048; epB += 2048; tq += 2048;
            }
            COMP2(a0, b0, t0); COMP2(a1, b1, t1); COMP2(a2, b2, t2); COMP2(a3, b3, t3);
            for (int k2 = 4; c + k2 < nch; ++k2) {
                a0 = LDE(epA + k2 * 512); b0 = LDE(epB + k2 * 512); t0 = LDE(tq + k2 * 512);
                COMP2(a0, b0, t0);
            }
#pragma unroll
            for (int r = 0; r < 4; ++r) {
                red[wave][0][kgrp * 4 + r][rowl] = 256.f * acc1A[r] + acc2A[r];
                red[wave][1][kgrp * 4 + r][rowl] = 256.f * acc1B[r] + acc2B[r];
            }
            __syncthreads();
            if (tid < 256) {
                int m32 = tid >> 3, n = tid & 7;
                int ph = m32 >> 4, m = m32 & 15;
                float sum = 0.f;
#pragma unroll
                for (int w = 0; w < 16; ++w)
                    sum += red[w][ph][m][n] + red[w][ph][m][n + 8];
                int r = blk * 32 + m32;
                float val = Tc[r * 8 + n] + S[r] * sum;
                const float* Brow = Bmat + r * 17;
#pragma unroll
                for (int j = 0; j < 17; ++j) val += Brow[j] * ush[j][n];
                stfc(&Tn[r * 8 + n], val);
                unsigned short hb = f2bf(val);
                int kg = m32 >> 3, j2 = m32 & 7;
                size_t tb = (size_t)blk * 512 + kg * 128;
                stu16c(&TTn[tb + n * 8 + j2], hb);
                stu16c(&TTn[tb + (n + 8) * 8 + j2], f2bf(val - bf2f(hb)));
            }
        } else {
            if (s >= 1 && wave < 8)
                mlp_batch_rot(Tc, ts, mwrite, ys, s - 1, wave, lane);
        }
        ++iter; gsync2(grpCnt, superCnt, gEpoch, iter);
    }
    // final MLP: theta_64 is slot 0
    if (blk == 199 && wave < 8)
        mlp_batch_rot(Tbase, ts, mbase, ys, TSTEPS - 1, wave, lane);
}

// ---------- fallback path (multi-launch, int16 E, fragment-linear theta) ----------
template<bool USE_E>
__global__ __launch_bounds__(128) void partial_kernel(
    const short* __restrict__ Eq, const float* __restrict__ S,
    const float* __restrict__ Af,
    const unsigned short* __restrict__ TTc,
    float* __restrict__ P)
{
    int blk = blockIdx.x;
    int p  = blk >> 3;
    int si = blk & 7;
    int tid = threadIdx.x;
    int wave = tid >> 6;
    int lane = tid & 63;
    int rowl = lane & 15;
    int kgrp = lane >> 4;
    int row = p * 16 + rowl;
    int c0 = si * CPS;
    int c1 = c0 + CPS; if (c1 > NCHUNK) c1 = NCHUNK;
    int nch = c1 - c0;
    int half = (nch + 1) >> 1;
    int csw = c0 + wave * half;
    int cew = csw + half; if (cew > c1) cew = c1;
    floatx4 acc1 = {0.f, 0.f, 0.f, 0.f};
    floatx4 acc2 = {0.f, 0.f, 0.f, 0.f};
    for (int c = csw; c < cew; ++c) {
        int k = c * 32 + kgrp * 8;
        short8v ehf, elf;
        if (USE_E) {
            short8v ev = *reinterpret_cast<const short8v*>(
                Eq + ((size_t)(p * NCHUNK + c)) * 512 + lane * 8);
            union { short8v sv; unsigned short us[8]; } EH, EL;
#pragma unroll
            for (int j = 0; j < 8; ++j) {
                int q = ev[j];
                union { float f; unsigned u; } ch2, cl2;
                ch2.f = (float)(q >> 8);
                cl2.f = (float)(q & 255);
                EH.us[j] = (unsigned short)(ch2.u >> 16);
                EL.us[j] = (unsigned short)(cl2.u >> 16);
            }
            ehf = EH.sv; elf = EL.sv;
        } else {
            const float* ap = Af + (size_t)row * LATENT + k;
            float v[8];
#pragma unroll
            for (int j = 0; j < 8; ++j) v[j] = ap[j];
            int jd = row - k;
            if (jd >= 0 && jd < 8) v[jd] -= 1.0f;
            union { short8v sv; unsigned short us[8]; } ch, cl;
#pragma unroll
            for (int j = 0; j < 8; ++j) {
                unsigned short hb = f2bf(v[j]);
                ch.us[j] = hb;
                cl.us[j] = f2bf(v[j] - bf2f(hb));
            }
            ehf = ch.sv; elf = cl.sv;
        }
        short8v tpf = *reinterpret_cast<const short8v*>(TTc + (size_t)c * 512 + lane * 8);
        acc1 = __builtin_amdgcn_mfma_f32_16x16x32_bf16(ehf, tpf, acc1, 0, 0, 0);
        acc2 = __builtin_amdgcn_mfma_f32_16x16x32_bf16(elf, tpf, acc2, 0, 0, 0);
    }
    __shared__ float red[2][16][16];
#pragma unroll
    for (int r = 0; r < 4; ++r)
        red[wave][kgrp * 4 + r][rowl] = USE_E ? (256.f * acc1[r] + acc2[r])
                                              : (acc1[r] + acc2[r]);
    __syncthreads();
    int nn = tid & 15;
    if (nn < 8) {
        for (int mm = tid >> 4; mm < 16; mm += 8) {
            float s2 = red[0][mm][nn] + red[0][mm][nn + 8]
                     + red[1][mm][nn] + red[1][mm][nn + 8];
            if (USE_E) s2 *= S[p * 16 + mm];
            P[((size_t)(p * 8 + si) * 16 + mm) * 8 + nn] = s2;
        }
    }
}

__global__ __launch_bounds__(256) void combine_kernel(
    const float* __restrict__ P,
    const float* __restrict__ Tcur,
    float* __restrict__ Tnxt,
    unsigned short* __restrict__ TTn,
    const float* __restrict__ Bmat,
    const float* __restrict__ xs,
    const float* __restrict__ ts,
    const float* __restrict__ mread,
    float* __restrict__ mwrite,
    float* __restrict__ ys,
    int s, int do_matvec, int do_mlp)
{
    int tid = threadIdx.x;
    if ((int)blockIdx.x < 199) {
        if (!do_matvec) return;
        __shared__ float u[17][8];
        if (tid < 136) {
            int b = tid & 7;
            int j = tid >> 3;
            float tc = ts[b * TSTEPS + s];
            float tp = (s == 0) ? -ts[b * TSTEPS + 1] : ts[b * TSTEPS + s - 1];
            float val;
            if (j == 0) val = tc - tp;
            else {
                int d = j - 1;
                float xp = (s < 2) ? xs[(b * TSTEPS) * NDATA + d] : mread[b * NDATA + d];
                val = xs[(b * TSTEPS + s) * NDATA + d] - xp;
            }
            u[j][b] = val;
        }
        __syncthreads();
        int idx = blockIdx.x * 256 + tid;
        int r = idx >> 3;
        int n = idx & 7;
        int pp = r >> 4, mm = r & 15;
        const float* Pb = P + ((size_t)pp * 8) * 128 + mm * 8 + n;
        float sum = 0.f;
#pragma unroll
        for (int si = 0; si < KSPLIT; ++si) sum += Pb[si * 128];
        float val = Tcur[r * 8 + n] + sum;
        const float* Brow = Bmat + r * 17;
#pragma unroll
        for (int j = 0; j < 17; ++j) val += Brow[j] * u[j][n];
        Tnxt[r * 8 + n] = val;
        unsigned short hb = f2bf(val);
        int c2 = r >> 5, kg = (r & 31) >> 3, j2 = r & 7;
        size_t tb = (size_t)c2 * 512 + kg * 128;
        TTn[tb + n * 8 + j2] = hb;
        TTn[tb + (n + 8) * 8 + j2] = f2bf(val - bf2f(hb));
    } else {
        if (!do_mlp) return;
        int w = tid >> 6, lane = tid & 63;
        for (int it = 0; it < 2; ++it)
            mlp_batch(Tcur, ts, mwrite, ys, s - 1, w * 2 + it, lane);
    }
}

extern "C" void kernel_launch(void* const* d_in, const int* in_sizes, int n_in,
                              void* d_out, int out_size, void* d_ws, size_t ws_size,
                              hipStream_t stream) {
    const float* xs  = (const float*)d_in[0];
    const float* ts  = (const float*)d_in[1];
    const float* A   = (const float*)d_in[2];
    const float* Bm  = (const float*)d_in[3];
    const float* th0 = (const float*)d_in[4];
    float* ys = (float*)d_out;

    char* ws = (char*)d_ws;
    size_t off = 0;
    auto alloc = [&](size_t bytes) {
        void* p = ws + off;
        off += (bytes + 255) & ~(size_t)255;
        return p;
    };
    float* Tbase = (float*)alloc((size_t)65 * TSTR * sizeof(float));          // 13.3 MB
    unsigned short* TTbase = (unsigned short*)alloc((size_t)65 * TTSTR * 2);  // 13.3 MB
    float* mbase = (float*)alloc((size_t)66 * 128 * sizeof(float));
    float* P  = (float*)alloc((size_t)NTILE * 128 * sizeof(float));
    float* S  = (float*)alloc((size_t)LATENT * sizeof(float));
    unsigned* bar = (unsigned*)alloc(8192);
    unsigned* grpCnt   = bar;             // 16 lines x 128B
    unsigned* superCnt = bar + 512;       // own line
    unsigned* gEpoch   = bar + 544;       // 16 lines x 128B
    size_t Ebytes = (size_t)NPANEL * NCHUNK * 512 * 2;   // int16 fragment-linear: 81 MB
    bool useE = (off + Ebytes + 512) <= ws_size;
    short* Eq = nullptr;
    if (useE) {
        Eq = (short*)alloc(Ebytes);
        row_scale<<<dim3(LATENT), dim3(64), 0, stream>>>(A, S);
        int nthr = LATENT * KBLK;         // NOT divisible by 256: ceil + guard
        convert_Eq<<<dim3((nthr + 255) / 256), dim3(256), 0, stream>>>(A, S, Eq, nthr);
    }
    // theta_0 lives at slot 64 (descending rotation)
    init_theta<<<dim3((LATENT + 255) / 256), dim3(256), 0, stream>>>(
        th0, Tbase + (size_t)64 * TSTR, TTbase + (size_t)64 * TTSTR);

    hipError_t coop = hipErrorUnknown;
    if (useE) {
        hipMemsetAsync(bar, 0, 8192, stream);
        void* kargs[] = {
            (void*)&Eq, (void*)&S, (void*)&Tbase, (void*)&TTbase,
            (void*)&mbase, (void*)&Bm, (void*)&xs,
            (void*)&ts, (void*)&ys, (void*)&grpCnt, (void*)&superCnt, (void*)&gEpoch };
        coop = hipLaunchCooperativeKernel((void*)persistent9,
                                          dim3(200), dim3(1024), kargs, 0, stream);
    }
    if (coop != hipSuccess) {
        // fallback: multi-launch path (kernel-boundary coherence; slots 64/63 ping-pong)
        float* T[2] = {Tbase + (size_t)64 * TSTR, Tbase + (size_t)63 * TSTR};
        unsigned short* TT[2] = {TTbase + (size_t)64 * TTSTR, TTbase + (size_t)63 * TTSTR};
        for (int s = 0; s <= TSTEPS; ++s) {
            int cur = s & 1, nxt = cur ^ 1;
            float* mwrite = mbase + (s & 1) * 128;
            float* mread  = mbase + ((s & 1) ^ 1) * 128;
            int dmv = (s < TSTEPS) ? 1 : 0;
            int dml = (s >= 1) ? 1 : 0;
            if (dmv) {
                if (useE)
                    partial_kernel<true><<<dim3(NTILE), dim3(128), 0, stream>>>(
                        Eq, S, A, TT[cur], P);
                else
                    partial_kernel<false><<<dim3(NTILE), dim3(128), 0, stream>>>(
                        Eq, S, A, TT[cur], P);
            }
            combine_kernel<<<dim3(200), dim3(256), 0, stream>>>(
                P, T[cur], T[nxt], TT[nxt],
                Bm, xs, ts, mread, mwrite, ys, s, dmv, dml);
        }
    }
    (void)in_sizes; (void)n_in; (void)out_size;
}